// Round 10
// baseline (526.492 us; speedup 1.0000x reference)
//
#include <hip/hip_runtime.h>

#define N_NODES 100000
#define N_EDGES 1600000
#define CAP 64

typedef unsigned short ushort_t;
typedef __attribute__((ext_vector_type(8))) short bf16x8;
typedef __attribute__((ext_vector_type(4))) float f32x4;
typedef __attribute__((ext_vector_type(4))) int int4e;
typedef __attribute__((ext_vector_type(4))) unsigned short ushort4e;

__device__ __forceinline__ unsigned short f2bf(float f) {
  unsigned int u = __float_as_uint(f);
  u = (u + 0x7FFFu + ((u >> 16) & 1u)) >> 16;
  return (unsigned short)u;
}

// ---- fused: deg atomics (blocks 0-6249) | pack X,H->U bf16 (6250-18749) | B^T+bias (18750-19773) ----
__global__ __launch_bounds__(256) void k_misc(
    const int* __restrict__ ei, const float* __restrict__ ew,
    const float* __restrict__ X, const float* __restrict__ H,
    float* __restrict__ deg, ushort_t* __restrict__ U,
    const float* __restrict__ W, const float* __restrict__ b,
    const float* __restrict__ cW, const float* __restrict__ cb,
    ushort_t* __restrict__ Bt, float* __restrict__ bias) {
  int bid = blockIdx.x;
  if (bid < 6250) {                       // deg[row] += ew  (atomic-latency-bound)
    int e = bid * 256 + threadIdx.x;
    atomicAdd(&deg[ei[e]], ew[e]);
  } else if (bid < 18750) {               // pack X (cols 0-127), H (cols 128-255)
    int i = (bid - 6250) * 256 + threadIdx.x;
    int n = i >> 5, q = i & 31;
    float4 x = *(const float4*)(X + (size_t)n * 128 + q * 4);
    float4 h = *(const float4*)(H + (size_t)n * 128 + q * 4);
    ushort4 a, bb;
    a.x = f2bf(x.x); a.y = f2bf(x.y); a.z = f2bf(x.z); a.w = f2bf(x.w);
    bb.x = f2bf(h.x); bb.y = f2bf(h.y); bb.z = f2bf(h.z); bb.w = f2bf(h.w);
    *(ushort4*)(U + (size_t)n * 512 + q * 4) = a;
    *(ushort4*)(U + (size_t)n * 512 + 128 + q * 4) = bb;
  } else {                                // B^T [512 j][512 k], j = d*4+g; bias
    int idx = (bid - 18750) * 256 + threadIdx.x;
    int j = idx >> 9, k = idx & 511;
    int dd = j >> 2, g = j & 3;
    float v;
    if (k < 128) v = W[(g * 128 + k) * 128 + dd];
    else {
      int kk = k - 128;
      int blk = kk >> 7;
      v = cW[((g * 3 + blk) * 128 + (kk & 127)) * 128 + dd];
    }
    Bt[idx] = f2bf(v);
    if (k == 0) bias[j] = b[g * 128 + dd] + cb[g * 128 + dd];
  }
}

// ---- bucket edges by dst, storing (row, rsqrt(deg[row])*ew); dinv[c] applied in gather ----
__global__ void k_bucket(const int* __restrict__ ei, const float* __restrict__ ew,
                         const float* __restrict__ deg, int* __restrict__ cnt,
                         int2* __restrict__ bE) {
  int e = blockIdx.x * 256 + threadIdx.x;
  if (e >= N_EDGES) return;
  int r = ei[e], c = ei[N_EDGES + e];
  float dr = deg[r];
  float s = dr > 0.f ? rsqrtf(dr) * ew[e] : 0.f;
  int pos = atomicAdd(&cnt[c], 1);
  if (pos < CAP) bE[c * CAP + pos] = make_int2(r, __float_as_int(s));
}

#define FMA4(A, W, V) \
  A.x = fmaf(W, V.x, A.x); A.y = fmaf(W, V.y, A.y); \
  A.z = fmaf(W, V.z, A.z); A.w = fmaf(W, V.w, A.w);

// load 4 bf16 (8B) from U row `p`, convert to f32
#define GATH(vv, p) { \
  ushort4 rw = *(const ushort4*)(sb + (size_t)(p) * 512); \
  vv.x = __uint_as_float((unsigned)rw.x << 16); \
  vv.y = __uint_as_float((unsigned)rw.y << 16); \
  vv.z = __uint_as_float((unsigned)rw.z << 16); \
  vv.w = __uint_as_float((unsigned)rw.w << 16); }

// ---- bf16-source gather: 32 lanes/node, 8 nodes/block (256 thr), 8-deep ILP ----
// PHASE 1: T1 = L_hat @ bf16(H)   (src U+128) -> U cols 256..383
// PHASE 2: T2 = 2*L_hat @ bf16(T1) - H (src U+256) -> U cols 384..511
template <int PHASE>
__global__ __launch_bounds__(256) void k_gather(
    const int* __restrict__ cnt, const int2* __restrict__ bE,
    const float* __restrict__ deg, const float* __restrict__ H,
    ushort_t* __restrict__ U) {
  int g = threadIdx.x >> 5, lane = threadIdx.x & 31;
  int node = blockIdx.x * 8 + g;
  if (node >= N_NODES) return;
  int cn = cnt[node]; if (cn > CAP) cn = CAP;
  const int2* be = bE + node * CAP;
  const ushort_t* sb = U + (PHASE == 1 ? 128 : 256) + lane * 4;
  float dc = deg[node];
  float sc = dc > 0.f ? -rsqrtf(dc) : 0.f;   // -dinv[c], factored out of the sum

  float4 z = {0.f, 0.f, 0.f, 0.f};
  float4 a0 = z, a1 = z, a2 = z, a3 = z, a4 = z, a5 = z, a6 = z, a7 = z;
  int i = 0;
  for (; i + 8 <= cn; i += 8) {
    int4e p0 = __builtin_nontemporal_load((const int4e*)(be + i));
    int4e p1 = __builtin_nontemporal_load((const int4e*)(be + i + 2));
    int4e p2 = __builtin_nontemporal_load((const int4e*)(be + i + 4));
    int4e p3 = __builtin_nontemporal_load((const int4e*)(be + i + 6));
    float4 v0, v1, v2, v3, v4, v5, v6, v7;
    GATH(v0, p0.x); GATH(v1, p0.z); GATH(v2, p1.x); GATH(v3, p1.z);
    GATH(v4, p2.x); GATH(v5, p2.z); GATH(v6, p3.x); GATH(v7, p3.z);
    FMA4(a0, __int_as_float(p0.y), v0); FMA4(a1, __int_as_float(p0.w), v1);
    FMA4(a2, __int_as_float(p1.y), v2); FMA4(a3, __int_as_float(p1.w), v3);
    FMA4(a4, __int_as_float(p2.y), v4); FMA4(a5, __int_as_float(p2.w), v5);
    FMA4(a6, __int_as_float(p3.y), v6); FMA4(a7, __int_as_float(p3.w), v7);
  }
  for (; i + 4 <= cn; i += 4) {
    int4e p0 = __builtin_nontemporal_load((const int4e*)(be + i));
    int4e p1 = __builtin_nontemporal_load((const int4e*)(be + i + 2));
    float4 v0, v1, v2, v3;
    GATH(v0, p0.x); GATH(v1, p0.z); GATH(v2, p1.x); GATH(v3, p1.z);
    FMA4(a0, __int_as_float(p0.y), v0); FMA4(a1, __int_as_float(p0.w), v1);
    FMA4(a2, __int_as_float(p1.y), v2); FMA4(a3, __int_as_float(p1.w), v3);
  }
  for (; i < cn; ++i) {
    int2 p = be[i];
    float4 v;
    GATH(v, p.x);
    FMA4(a0, __int_as_float(p.y), v);
  }
  float4 acc;
  acc.x = sc * (((a0.x + a1.x) + (a2.x + a3.x)) + ((a4.x + a5.x) + (a6.x + a7.x)));
  acc.y = sc * (((a0.y + a1.y) + (a2.y + a3.y)) + ((a4.y + a5.y) + (a6.y + a7.y)));
  acc.z = sc * (((a0.z + a1.z) + (a2.z + a3.z)) + ((a4.z + a5.z) + (a6.z + a7.z)));
  acc.w = sc * (((a0.w + a1.w) + (a2.w + a3.w)) + ((a4.w + a5.w) + (a6.w + a7.w)));

  if (PHASE == 1) {
    ushort4e u = {f2bf(acc.x), f2bf(acc.y), f2bf(acc.z), f2bf(acc.w)};
    __builtin_nontemporal_store(u, (ushort4e*)(U + (size_t)node * 512 + 256 + lane * 4));
  } else {
    float4 h = *(const float4*)(H + (size_t)node * 128 + lane * 4);
    ushort4e u = {f2bf(2.f * acc.x - h.x), f2bf(2.f * acc.y - h.y),
                  f2bf(2.f * acc.z - h.z), f2bf(2.f * acc.w - h.w)};
    __builtin_nontemporal_store(u, (ushort4e*)(U + (size_t)node * 512 + 384 + lane * 4));
  }
}

// ---- fused GEMM: A via LDS dbuf (2x16KB), B fragments direct from L2, 4 blocks/CU ----
__global__ __launch_bounds__(256, 4) void k_gemm(
    const ushort_t* __restrict__ U, const ushort_t* __restrict__ Bt,
    const float* __restrict__ bias, const float* __restrict__ C,
    float* __restrict__ out) {
  __shared__ char ldsRaw[33792];     // A dbuf 2x16KB; epilogue reuses as 64x132 f32 tile
  char* ldsA0 = ldsRaw;
  char* ldsA1 = ldsRaw + 16384;
  float* ldsF = (float*)ldsRaw;

  const int tid = threadIdx.x;
  const int lane = tid & 63;
  const int w = tid >> 6;
  const int wr = w >> 1, wc = w & 1;
  // XCD-bijective swizzle: 3128 = 8*391; 4 n-tiles of an m-panel stay in one XCD
  const int b = blockIdx.x;
  const int g = (b & 7) * 391 + (b >> 3);
  const int m0 = (g >> 2) * 128;
  const int n0 = (g & 3) * 128;
  const int l15 = lane & 15;
  const int l4 = lane >> 4;

  auto stageA = [&](int kt, char* la_base) {   // 4 x global_load_lds(16B) per thread
    const int k0 = kt * 64;
#pragma unroll
    for (int is = 0; is < 4; ++is) {
      int s = is * 256 + tid;
      int row = s >> 3;
      int cs = (s & 7) ^ (row & 7);            // inverse-swizzled global source chunk
      const ushort_t* ga = U + (size_t)(m0 + row) * 512 + k0 + cs * 8;
      char* la = la_base + (is * 256 + (tid & 192)) * 16;   // wave-uniform base
      __builtin_amdgcn_global_load_lds((const __attribute__((address_space(1))) void*)ga,
                                       (__attribute__((address_space(3))) void*)la, 16, 0, 0);
    }
  };

  // loop-invariant swizzled LDS read offsets for A (row&7 == l15&7)
  int offA[2][4];
#pragma unroll
  for (int ks = 0; ks < 2; ++ks) {
    int slot = ((ks * 4 + l4) ^ (l15 & 7)) * 16;
#pragma unroll
    for (int i = 0; i < 4; ++i)
      offA[ks][i] = (wr * 64 + i * 16 + l15) * 128 + slot;
  }
  // per-lane B base (B stays in L2: 0.5 MB shared by all blocks)
  const ushort_t* Bb = Bt + (size_t)(n0 + wc * 64 + l15) * 512 + l4 * 8;

  f32x4 acc[4][4] = {};

  stageA(0, ldsA0);                        // 4 vm ops outstanding (invariant at iter entry)

  for (int kt = 0; kt < 8; ++kt) {
    char* cur = (kt & 1) ? ldsA1 : ldsA0;
    char* nxt = (kt & 1) ? ldsA0 : ldsA1;
    // issue order: b0(4), b1(4), stageA(kt+1)(4) -> compiler's waits for b0/b1
    // (vmcnt 8/4) never drain the A prefetch; manual wait hits exactly A(kt).
    bf16x8 b0[4], b1[4];
#pragma unroll
    for (int ni = 0; ni < 4; ++ni)
      b0[ni] = *(const bf16x8*)(Bb + ni * 16 * 512 + kt * 64);
#pragma unroll
    for (int ni = 0; ni < 4; ++ni)
      b1[ni] = *(const bf16x8*)(Bb + ni * 16 * 512 + kt * 64 + 32);
    __builtin_amdgcn_sched_barrier(0);
    if (kt < 7) {
      stageA(kt + 1, nxt);
      __builtin_amdgcn_sched_barrier(0);
      asm volatile("s_waitcnt vmcnt(12)" ::: "memory");  // A(kt) landed; b0,b1,A(kt+1) in flight
    } else {
      asm volatile("s_waitcnt vmcnt(8)" ::: "memory");   // A(7) landed; b0,b1 in flight
    }
    __builtin_amdgcn_s_barrier();          // A: cur fully staged for all threads
    __builtin_amdgcn_sched_barrier(0);
    // ks0
    {
      bf16x8 af[4];
#pragma unroll
      for (int mi = 0; mi < 4; ++mi) af[mi] = *(const bf16x8*)(cur + offA[0][mi]);
      __builtin_amdgcn_s_setprio(1);
#pragma unroll
      for (int mi = 0; mi < 4; ++mi)
#pragma unroll
        for (int ni = 0; ni < 4; ++ni)
          acc[mi][ni] = __builtin_amdgcn_mfma_f32_16x16x32_bf16(af[mi], b0[ni], acc[mi][ni], 0, 0, 0);
      __builtin_amdgcn_s_setprio(0);
    }
    // ks1
    {
      bf16x8 af[4];
#pragma unroll
      for (int mi = 0; mi < 4; ++mi) af[mi] = *(const bf16x8*)(cur + offA[1][mi]);
      __builtin_amdgcn_s_setprio(1);
#pragma unroll
      for (int mi = 0; mi < 4; ++mi)
#pragma unroll
        for (int ni = 0; ni < 4; ++ni)
          acc[mi][ni] = __builtin_amdgcn_mfma_f32_16x16x32_bf16(af[mi], b1[ni], acc[mi][ni], 0, 0, 0);
      __builtin_amdgcn_s_setprio(0);
    }
    asm volatile("s_waitcnt lgkmcnt(0)" ::: "memory");   // my LDS reads of cur complete
    __builtin_amdgcn_sched_barrier(0);
    __builtin_amdgcn_s_barrier();          // B: all done reading cur; safe to overwrite
  }

  // epilogue: two row-halves through LDS, then fused LSTM elementwise
#pragma unroll
  for (int half = 0; half < 2; ++half) {
    if (wr == half) {
#pragma unroll
      for (int ni = 0; ni < 4; ++ni) {
        int col = wc * 64 + ni * 16 + l15;
        float bv = bias[n0 + col];
#pragma unroll
        for (int mi = 0; mi < 4; ++mi)
#pragma unroll
          for (int r = 0; r < 4; ++r)
            ldsF[(mi * 16 + l4 * 4 + r) * 132 + col] = acc[mi][ni][r] + bv;
      }
    }
    __syncthreads();
#pragma unroll
    for (int k = 0; k < 8; ++k) {
      int p = tid + k * 256;
      int rl = p >> 5, f = p & 31;
      int n = m0 + half * 64 + rl;
      if (n < N_NODES) {
        float4 pre = *(const float4*)&ldsF[rl * 132 + f * 4];
        int dg = (n0 >> 2) + f;
        float ig = __builtin_amdgcn_rcpf(1.f + __expf(-pre.x));
        float fg = __builtin_amdgcn_rcpf(1.f + __expf(-pre.y));
        float ec = __expf(-2.f * fabsf(pre.z));
        float tg = __builtin_copysignf((1.f - ec) * __builtin_amdgcn_rcpf(1.f + ec), pre.z);
        float og = __builtin_amdgcn_rcpf(1.f + __expf(-pre.w));
        float cOld = C[(size_t)n * 128 + dg];
        float cn = fg * cOld + ig * tg;
        float en = __expf(-2.f * fabsf(cn));
        float th = __builtin_copysignf((1.f - en) * __builtin_amdgcn_rcpf(1.f + en), cn);
        out[(size_t)n * 128 + dg] = og * th;
      }
    }
    __syncthreads();
  }
}

extern "C" void kernel_launch(void* const* d_in, const int* in_sizes, int n_in,
                              void* d_out, int out_size, void* d_ws, size_t ws_size,
                              hipStream_t stream) {
  const float* X  = (const float*)d_in[0];
  const int*   ei = (const int*)d_in[1];
  const float* ew = (const float*)d_in[2];
  const float* H  = (const float*)d_in[3];
  const float* C  = (const float*)d_in[4];
  const float* W  = (const float*)d_in[5];
  const float* b  = (const float*)d_in[6];
  const float* cW = (const float*)d_in[7];
  const float* cb = (const float*)d_in[8];
  float* out = (float*)d_out;
  char* ws = (char*)d_ws;

  float*    deg  = (float*)(ws);                 // 0.5 MB
  int*      cnt  = (int*)(ws + 0x80000);         // 0.5 MB
  int2*     bE   = (int2*)(ws + 0x100000);       // 51.2 MB CAP buckets (row, s)
  ushort_t* U    = (ushort_t*)(ws + 0x3500000);  // 100096 x 512 bf16 = 102.5 MB
  ushort_t* Bt   = (ushort_t*)(ws + 0x9700000);  // 512 KB
  float*    bias = (float*)(ws + 0x9780000);     // 2 KB

  hipMemsetAsync(ws, 0, 0x100000, stream);       // zero deg + cnt

  k_misc<<<19774, 256, 0, stream>>>(ei, ew, X, H, deg, U, W, b, cW, cb, Bt, bias);
  k_bucket<<<(N_EDGES + 255) / 256, 256, 0, stream>>>(ei, ew, deg, cnt, bE);
  k_gather<1><<<(N_NODES + 7) / 8, 256, 0, stream>>>(cnt, bE, deg, H, U);
  k_gather<2><<<(N_NODES + 7) / 8, 256, 0, stream>>>(cnt, bE, deg, H, U);
  k_gemm<<<3128, 256, 0, stream>>>(U, Bt, bias, C, out);
}

// Round 12
// 515.750 us; speedup vs baseline: 1.0208x; 1.0208x over previous
//
#include <hip/hip_runtime.h>

#define N_NODES 100000
#define N_EDGES 1600000
#define CAP 64

typedef unsigned short ushort_t;
typedef __attribute__((ext_vector_type(8))) short bf16x8;
typedef __attribute__((ext_vector_type(4))) float f32x4;
typedef __attribute__((ext_vector_type(4))) int int4e;
typedef __attribute__((ext_vector_type(4))) unsigned short ushort4e;

__device__ __forceinline__ unsigned short f2bf(float f) {
  unsigned int u = __float_as_uint(f);
  u = (u + 0x7FFFu + ((u >> 16) & 1u)) >> 16;
  return (unsigned short)u;
}

// ---- fused: deg atomics (blocks 0-6249) | pack X,H->U bf16 (6250-18749) | B^T+bias (18750-19773) ----
__global__ __launch_bounds__(256) void k_misc(
    const int* __restrict__ ei, const float* __restrict__ ew,
    const float* __restrict__ X, const float* __restrict__ H,
    float* __restrict__ deg, ushort_t* __restrict__ U,
    const float* __restrict__ W, const float* __restrict__ b,
    const float* __restrict__ cW, const float* __restrict__ cb,
    ushort_t* __restrict__ Bt, float* __restrict__ bias) {
  int bid = blockIdx.x;
  if (bid < 6250) {                       // deg[row] += ew  (atomic-latency-bound)
    int e = bid * 256 + threadIdx.x;
    atomicAdd(&deg[ei[e]], ew[e]);
  } else if (bid < 18750) {               // pack X (cols 0-127), H (cols 128-255)
    int i = (bid - 6250) * 256 + threadIdx.x;
    int n = i >> 5, q = i & 31;
    float4 x = *(const float4*)(X + (size_t)n * 128 + q * 4);
    float4 h = *(const float4*)(H + (size_t)n * 128 + q * 4);
    ushort4 a, bb;
    a.x = f2bf(x.x); a.y = f2bf(x.y); a.z = f2bf(x.z); a.w = f2bf(x.w);
    bb.x = f2bf(h.x); bb.y = f2bf(h.y); bb.z = f2bf(h.z); bb.w = f2bf(h.w);
    *(ushort4*)(U + (size_t)n * 512 + q * 4) = a;
    *(ushort4*)(U + (size_t)n * 512 + 128 + q * 4) = bb;
  } else {                                // B^T [512 j][512 k], j = d*4+g; bias
    int idx = (bid - 18750) * 256 + threadIdx.x;
    int j = idx >> 9, k = idx & 511;
    int dd = j >> 2, g = j & 3;
    float v;
    if (k < 128) v = W[(g * 128 + k) * 128 + dd];
    else {
      int kk = k - 128;
      int blk = kk >> 7;
      v = cW[((g * 3 + blk) * 128 + (kk & 127)) * 128 + dd];
    }
    Bt[idx] = f2bf(v);
    if (k == 0) bias[j] = b[g * 128 + dd] + cb[g * 128 + dd];
  }
}

// ---- bucket edges by dst, storing (row, rsqrt(deg[row])*ew); dinv[c] applied in gather ----
__global__ void k_bucket(const int* __restrict__ ei, const float* __restrict__ ew,
                         const float* __restrict__ deg, int* __restrict__ cnt,
                         int2* __restrict__ bE) {
  int e = blockIdx.x * 256 + threadIdx.x;
  if (e >= N_EDGES) return;
  int r = ei[e], c = ei[N_EDGES + e];
  float dr = deg[r];
  float s = dr > 0.f ? rsqrtf(dr) * ew[e] : 0.f;
  int pos = atomicAdd(&cnt[c], 1);
  if (pos < CAP) bE[c * CAP + pos] = make_int2(r, __float_as_int(s));
}

#define FMA4(A, W, V) \
  A.x = fmaf(W, V.x, A.x); A.y = fmaf(W, V.y, A.y); \
  A.z = fmaf(W, V.z, A.z); A.w = fmaf(W, V.w, A.w);

// load 4 bf16 (8B) from U row `p`, convert to f32
#define GATH(vv, p) { \
  ushort4 rw = *(const ushort4*)(sb + (size_t)(p) * 512); \
  vv.x = __uint_as_float((unsigned)rw.x << 16); \
  vv.y = __uint_as_float((unsigned)rw.y << 16); \
  vv.z = __uint_as_float((unsigned)rw.z << 16); \
  vv.w = __uint_as_float((unsigned)rw.w << 16); }

// ---- bf16-source gather: 32 lanes/node, 8 nodes/block (256 thr), 8-deep ILP ----
// PHASE 1: T1 = L_hat @ bf16(H)   (src U+128) -> U cols 256..383
// PHASE 2: T2 = 2*L_hat @ bf16(T1) - H (src U+256) -> U cols 384..511
template <int PHASE>
__global__ __launch_bounds__(256) void k_gather(
    const int* __restrict__ cnt, const int2* __restrict__ bE,
    const float* __restrict__ deg, const float* __restrict__ H,
    ushort_t* __restrict__ U) {
  int g = threadIdx.x >> 5, lane = threadIdx.x & 31;
  int node = blockIdx.x * 8 + g;
  if (node >= N_NODES) return;
  int cn = cnt[node]; if (cn > CAP) cn = CAP;
  const int2* be = bE + node * CAP;
  const ushort_t* sb = U + (PHASE == 1 ? 128 : 256) + lane * 4;
  float dc = deg[node];
  float sc = dc > 0.f ? -rsqrtf(dc) : 0.f;   // -dinv[c], factored out of the sum

  float4 z = {0.f, 0.f, 0.f, 0.f};
  float4 a0 = z, a1 = z, a2 = z, a3 = z, a4 = z, a5 = z, a6 = z, a7 = z;
  int i = 0;
  for (; i + 8 <= cn; i += 8) {
    int4e p0 = __builtin_nontemporal_load((const int4e*)(be + i));
    int4e p1 = __builtin_nontemporal_load((const int4e*)(be + i + 2));
    int4e p2 = __builtin_nontemporal_load((const int4e*)(be + i + 4));
    int4e p3 = __builtin_nontemporal_load((const int4e*)(be + i + 6));
    float4 v0, v1, v2, v3, v4, v5, v6, v7;
    GATH(v0, p0.x); GATH(v1, p0.z); GATH(v2, p1.x); GATH(v3, p1.z);
    GATH(v4, p2.x); GATH(v5, p2.z); GATH(v6, p3.x); GATH(v7, p3.z);
    FMA4(a0, __int_as_float(p0.y), v0); FMA4(a1, __int_as_float(p0.w), v1);
    FMA4(a2, __int_as_float(p1.y), v2); FMA4(a3, __int_as_float(p1.w), v3);
    FMA4(a4, __int_as_float(p2.y), v4); FMA4(a5, __int_as_float(p2.w), v5);
    FMA4(a6, __int_as_float(p3.y), v6); FMA4(a7, __int_as_float(p3.w), v7);
  }
  for (; i + 4 <= cn; i += 4) {
    int4e p0 = __builtin_nontemporal_load((const int4e*)(be + i));
    int4e p1 = __builtin_nontemporal_load((const int4e*)(be + i + 2));
    float4 v0, v1, v2, v3;
    GATH(v0, p0.x); GATH(v1, p0.z); GATH(v2, p1.x); GATH(v3, p1.z);
    FMA4(a0, __int_as_float(p0.y), v0); FMA4(a1, __int_as_float(p0.w), v1);
    FMA4(a2, __int_as_float(p1.y), v2); FMA4(a3, __int_as_float(p1.w), v3);
  }
  for (; i < cn; ++i) {
    int2 p = be[i];
    float4 v;
    GATH(v, p.x);
    FMA4(a0, __int_as_float(p.y), v);
  }
  float4 acc;
  acc.x = sc * (((a0.x + a1.x) + (a2.x + a3.x)) + ((a4.x + a5.x) + (a6.x + a7.x)));
  acc.y = sc * (((a0.y + a1.y) + (a2.y + a3.y)) + ((a4.y + a5.y) + (a6.y + a7.y)));
  acc.z = sc * (((a0.z + a1.z) + (a2.z + a3.z)) + ((a4.z + a5.z) + (a6.z + a7.z)));
  acc.w = sc * (((a0.w + a1.w) + (a2.w + a3.w)) + ((a4.w + a5.w) + (a6.w + a7.w)));

  if (PHASE == 1) {
    ushort4e u = {f2bf(acc.x), f2bf(acc.y), f2bf(acc.z), f2bf(acc.w)};
    __builtin_nontemporal_store(u, (ushort4e*)(U + (size_t)node * 512 + 256 + lane * 4));
  } else {
    float4 h = *(const float4*)(H + (size_t)node * 128 + lane * 4);
    ushort4e u = {f2bf(2.f * acc.x - h.x), f2bf(2.f * acc.y - h.y),
                  f2bf(2.f * acc.z - h.z), f2bf(2.f * acc.w - h.w)};
    __builtin_nontemporal_store(u, (ushort4e*)(U + (size_t)node * 512 + 384 + lane * 4));
  }
}

// ---- fused GEMM: A via LDS dbuf, B via REGISTER dbuf (depth-2 both), 3 blocks/CU ----
__global__ __launch_bounds__(256, 3) void k_gemm(
    const ushort_t* __restrict__ U, const ushort_t* __restrict__ Bt,
    const float* __restrict__ bias, const float* __restrict__ C,
    float* __restrict__ out) {
  __shared__ char ldsRaw[33792];     // A dbuf 2x16KB; epilogue reuses as 64x132 f32 tile
  char* ldsA0 = ldsRaw;
  char* ldsA1 = ldsRaw + 16384;
  float* ldsF = (float*)ldsRaw;

  const int tid = threadIdx.x;
  const int lane = tid & 63;
  const int w = tid >> 6;
  const int wr = w >> 1, wc = w & 1;
  // XCD-bijective swizzle: 3128 = 8*391; 4 n-tiles of an m-panel stay in one XCD
  const int b = blockIdx.x;
  const int g = (b & 7) * 391 + (b >> 3);
  const int m0 = (g >> 2) * 128;
  const int n0 = (g & 3) * 128;
  const int l15 = lane & 15;
  const int l4 = lane >> 4;

  auto stageA = [&](int kt, char* la_base) {   // 4 x global_load_lds(16B) per thread
    const int k0 = kt * 64;
#pragma unroll
    for (int is = 0; is < 4; ++is) {
      int s = is * 256 + tid;
      int row = s >> 3;
      int cs = (s & 7) ^ (row & 7);            // inverse-swizzled global source chunk
      const ushort_t* ga = U + (size_t)(m0 + row) * 512 + k0 + cs * 8;
      char* la = la_base + (is * 256 + (tid & 192)) * 16;   // wave-uniform base
      __builtin_amdgcn_global_load_lds((const __attribute__((address_space(1))) void*)ga,
                                       (__attribute__((address_space(3))) void*)la, 16, 0, 0);
    }
  };

  // loop-invariant swizzled LDS read offsets for A (row&7 == l15&7)
  int offA[2][4];
#pragma unroll
  for (int ks = 0; ks < 2; ++ks) {
    int slot = ((ks * 4 + l4) ^ (l15 & 7)) * 16;
#pragma unroll
    for (int i = 0; i < 4; ++i)
      offA[ks][i] = (wr * 64 + i * 16 + l15) * 128 + slot;
  }
  // per-lane B base (B is 0.5 MB, L2-resident everywhere)
  const ushort_t* Bb = Bt + (size_t)(n0 + wc * 64 + l15) * 512 + l4 * 8;

// load the 8 B-fragments of K-step kt into named regs (explicit, no paste-with-loop-var)
#define LOADB(dst, kt) { \
  dst##0  = *(const bf16x8*)(Bb + 0 * 16 * 512 + (kt) * 64); \
  dst##1  = *(const bf16x8*)(Bb + 1 * 16 * 512 + (kt) * 64); \
  dst##2  = *(const bf16x8*)(Bb + 2 * 16 * 512 + (kt) * 64); \
  dst##3  = *(const bf16x8*)(Bb + 3 * 16 * 512 + (kt) * 64); \
  dst##0h = *(const bf16x8*)(Bb + 0 * 16 * 512 + (kt) * 64 + 32); \
  dst##1h = *(const bf16x8*)(Bb + 1 * 16 * 512 + (kt) * 64 + 32); \
  dst##2h = *(const bf16x8*)(Bb + 2 * 16 * 512 + (kt) * 64 + 32); \
  dst##3h = *(const bf16x8*)(Bb + 3 * 16 * 512 + (kt) * 64 + 32); }

  f32x4 acc[4][4] = {};
  bf16x8 bA0, bA1, bA2, bA3, bA0h, bA1h, bA2h, bA3h;
  bf16x8 bB0, bB1, bB2, bB3, bB0h, bB1h, bB2h, bB3h;

  LOADB(bA, 0);                            // 8 loads outstanding
  stageA(0, ldsA0);                        // +4 -> invariant at iter top: b(kt)(8), A(kt)(4)

// one K-step: prefetch b(kt+1)->bn*, A(kt+1)->nxt; compute from cur + bc*
#define ITER(kt, cur, nxt, bc, bn) { \
  if ((kt) < 7) { \
    LOADB(bn, (kt) + 1); \
    stageA((kt) + 1, nxt); \
    __builtin_amdgcn_sched_barrier(0); \
    asm volatile("s_waitcnt vmcnt(12)" ::: "memory");  /* b(kt)+A(kt) landed */ \
  } else { \
    asm volatile("s_waitcnt vmcnt(0)" ::: "memory"); \
  } \
  __builtin_amdgcn_s_barrier();            /* cur fully staged for all threads */ \
  __builtin_amdgcn_sched_barrier(0); \
  { \
    bf16x8 af[4]; \
    _Pragma("unroll") for (int mi = 0; mi < 4; ++mi) \
      af[mi] = *(const bf16x8*)(cur + offA[0][mi]); \
    __builtin_amdgcn_s_setprio(1); \
    _Pragma("unroll") for (int mi = 0; mi < 4; ++mi) { \
      acc[mi][0] = __builtin_amdgcn_mfma_f32_16x16x32_bf16(af[mi], bc##0, acc[mi][0], 0, 0, 0); \
      acc[mi][1] = __builtin_amdgcn_mfma_f32_16x16x32_bf16(af[mi], bc##1, acc[mi][1], 0, 0, 0); \
      acc[mi][2] = __builtin_amdgcn_mfma_f32_16x16x32_bf16(af[mi], bc##2, acc[mi][2], 0, 0, 0); \
      acc[mi][3] = __builtin_amdgcn_mfma_f32_16x16x32_bf16(af[mi], bc##3, acc[mi][3], 0, 0, 0); \
    } \
    __builtin_amdgcn_s_setprio(0); \
  } \
  { \
    bf16x8 af[4]; \
    _Pragma("unroll") for (int mi = 0; mi < 4; ++mi) \
      af[mi] = *(const bf16x8*)(cur + offA[1][mi]); \
    __builtin_amdgcn_s_setprio(1); \
    _Pragma("unroll") for (int mi = 0; mi < 4; ++mi) { \
      acc[mi][0] = __builtin_amdgcn_mfma_f32_16x16x32_bf16(af[mi], bc##0h, acc[mi][0], 0, 0, 0); \
      acc[mi][1] = __builtin_amdgcn_mfma_f32_16x16x32_bf16(af[mi], bc##1h, acc[mi][1], 0, 0, 0); \
      acc[mi][2] = __builtin_amdgcn_mfma_f32_16x16x32_bf16(af[mi], bc##2h, acc[mi][2], 0, 0, 0); \
      acc[mi][3] = __builtin_amdgcn_mfma_f32_16x16x32_bf16(af[mi], bc##3h, acc[mi][3], 0, 0, 0); \
    } \
    __builtin_amdgcn_s_setprio(0); \
  } \
  asm volatile("s_waitcnt lgkmcnt(0)" ::: "memory");   /* my LDS reads of cur done */ \
  __builtin_amdgcn_sched_barrier(0); \
  __builtin_amdgcn_s_barrier();            /* safe to overwrite cur */ }

  ITER(0, ldsA0, ldsA1, bA, bB);
  ITER(1, ldsA1, ldsA0, bB, bA);
  ITER(2, ldsA0, ldsA1, bA, bB);
  ITER(3, ldsA1, ldsA0, bB, bA);
  ITER(4, ldsA0, ldsA1, bA, bB);
  ITER(5, ldsA1, ldsA0, bB, bA);
  ITER(6, ldsA0, ldsA1, bA, bB);
  ITER(7, ldsA1, ldsA0, bB, bA);

  // epilogue: two row-halves through LDS, then fused LSTM elementwise
#pragma unroll
  for (int half = 0; half < 2; ++half) {
    if (wr == half) {
#pragma unroll
      for (int ni = 0; ni < 4; ++ni) {
        int col = wc * 64 + ni * 16 + l15;
        float bv = bias[n0 + col];
#pragma unroll
        for (int mi = 0; mi < 4; ++mi)
#pragma unroll
          for (int r = 0; r < 4; ++r)
            ldsF[(mi * 16 + l4 * 4 + r) * 132 + col] = acc[mi][ni][r] + bv;
      }
    }
    __syncthreads();
#pragma unroll
    for (int k = 0; k < 8; ++k) {
      int p = tid + k * 256;
      int rl = p >> 5, f = p & 31;
      int n = m0 + half * 64 + rl;
      if (n < N_NODES) {
        float4 pre = *(const float4*)&ldsF[rl * 132 + f * 4];
        int dg = (n0 >> 2) + f;
        float ig = __builtin_amdgcn_rcpf(1.f + __expf(-pre.x));
        float fg = __builtin_amdgcn_rcpf(1.f + __expf(-pre.y));
        float ec = __expf(-2.f * fabsf(pre.z));
        float tg = __builtin_copysignf((1.f - ec) * __builtin_amdgcn_rcpf(1.f + ec), pre.z);
        float og = __builtin_amdgcn_rcpf(1.f + __expf(-pre.w));
        float cOld = C[(size_t)n * 128 + dg];
        float cn = fg * cOld + ig * tg;
        float en = __expf(-2.f * fabsf(cn));
        float th = __builtin_copysignf((1.f - en) * __builtin_amdgcn_rcpf(1.f + en), cn);
        out[(size_t)n * 128 + dg] = og * th;
      }
    }
    __syncthreads();
  }
}

extern "C" void kernel_launch(void* const* d_in, const int* in_sizes, int n_in,
                              void* d_out, int out_size, void* d_ws, size_t ws_size,
                              hipStream_t stream) {
  const float* X  = (const float*)d_in[0];
  const int*   ei = (const int*)d_in[1];
  const float* ew = (const float*)d_in[2];
  const float* H  = (const float*)d_in[3];
  const float* C  = (const float*)d_in[4];
  const float* W  = (const float*)d_in[5];
  const float* b  = (const float*)d_in[6];
  const float* cW = (const float*)d_in[7];
  const float* cb = (const float*)d_in[8];
  float* out = (float*)d_out;
  char* ws = (char*)d_ws;

  float*    deg  = (float*)(ws);                 // 0.5 MB
  int*      cnt  = (int*)(ws + 0x80000);         // 0.5 MB
  int2*     bE   = (int2*)(ws + 0x100000);       // 51.2 MB CAP buckets (row, s)
  ushort_t* U    = (ushort_t*)(ws + 0x3500000);  // 100096 x 512 bf16 = 102.5 MB
  ushort_t* Bt   = (ushort_t*)(ws + 0x9700000);  // 512 KB
  float*    bias = (float*)(ws + 0x9780000);     // 2 KB

  hipMemsetAsync(ws, 0, 0x100000, stream);       // zero deg + cnt

  k_misc<<<19774, 256, 0, stream>>>(ei, ew, X, H, deg, U, W, b, cW, cb, Bt, bias);
  k_bucket<<<(N_EDGES + 255) / 256, 256, 0, stream>>>(ei, ew, deg, cnt, bE);
  k_gather<1><<<(N_NODES + 7) / 8, 256, 0, stream>>>(cnt, bE, deg, H, U);
  k_gather<2><<<(N_NODES + 7) / 8, 256, 0, stream>>>(cnt, bE, deg, H, U);
  k_gemm<<<3128, 256, 0, stream>>>(U, Bt, bias, C, out);
}

// Round 13
// 486.636 us; speedup vs baseline: 1.0819x; 1.0598x over previous
//
#include <hip/hip_runtime.h>

#define N_NODES 100000
#define N_EDGES 1600000
#define CAP 64

typedef unsigned short ushort_t;
typedef __attribute__((ext_vector_type(8))) short bf16x8;
typedef __attribute__((ext_vector_type(4))) float f32x4;
typedef __attribute__((ext_vector_type(4))) int int4e;
typedef __attribute__((ext_vector_type(4))) unsigned short ushort4e;

__device__ __forceinline__ unsigned short f2bf(float f) {
  unsigned int u = __float_as_uint(f);
  u = (u + 0x7FFFu + ((u >> 16) & 1u)) >> 16;
  return (unsigned short)u;
}

// ---- fused: per-edge {deg atomic + cnt atomic + (r, raw ew) scatter} (blocks 0-6249)
//      | pack X,H->U bf16 (6250-18749) | B^T+bias (18750-19773). Streaming blocks
//      hide under the atomic-throughput-bound edge blocks. ----
__global__ __launch_bounds__(256) void k_misc(
    const int* __restrict__ ei, const float* __restrict__ ew,
    const float* __restrict__ X, const float* __restrict__ H,
    float* __restrict__ deg, int* __restrict__ cnt, int2* __restrict__ bE,
    ushort_t* __restrict__ U,
    const float* __restrict__ W, const float* __restrict__ b,
    const float* __restrict__ cW, const float* __restrict__ cb,
    ushort_t* __restrict__ Bt, float* __restrict__ bias) {
  int bid = blockIdx.x;
  if (bid < 6250) {                       // both atomics + scatter, one thread per edge
    int e = bid * 256 + threadIdx.x;
    int r = ei[e], c = ei[N_EDGES + e];
    float w = ew[e];
    atomicAdd(&deg[r], w);
    int pos = atomicAdd(&cnt[c], 1);
    if (pos < CAP) bE[c * CAP + pos] = make_int2(r, __float_as_int(w));
  } else if (bid < 18750) {               // pack X (cols 0-127), H (cols 128-255)
    int i = (bid - 6250) * 256 + threadIdx.x;
    int n = i >> 5, q = i & 31;
    float4 x = *(const float4*)(X + (size_t)n * 128 + q * 4);
    float4 h = *(const float4*)(H + (size_t)n * 128 + q * 4);
    ushort4 a, bb;
    a.x = f2bf(x.x); a.y = f2bf(x.y); a.z = f2bf(x.z); a.w = f2bf(x.w);
    bb.x = f2bf(h.x); bb.y = f2bf(h.y); bb.z = f2bf(h.z); bb.w = f2bf(h.w);
    *(ushort4*)(U + (size_t)n * 512 + q * 4) = a;
    *(ushort4*)(U + (size_t)n * 512 + 128 + q * 4) = bb;
  } else {                                // B^T [512 j][512 k], j = d*4+g; bias
    int idx = (bid - 18750) * 256 + threadIdx.x;
    int j = idx >> 9, k = idx & 511;
    int dd = j >> 2, g = j & 3;
    float v;
    if (k < 128) v = W[(g * 128 + k) * 128 + dd];
    else {
      int kk = k - 128;
      int blk = kk >> 7;
      v = cW[((g * 3 + blk) * 128 + (kk & 127)) * 128 + dd];
    }
    Bt[idx] = f2bf(v);
    if (k == 0) bias[j] = b[g * 128 + dd] + cb[g * 128 + dd];
  }
}

// ---- post-pass: bE[slot].w = rsqrt(deg[row]) * raw_ew (deg now complete) ----
__global__ __launch_bounds__(256) void k_scale(
    const int* __restrict__ cnt, const float* __restrict__ deg,
    int2* __restrict__ bE) {
  int slot = blockIdx.x * 256 + threadIdx.x;     // grid covers N_NODES*CAP exactly
  int node = slot >> 6, i = slot & 63;
  int cn = cnt[node]; if (cn > CAP) cn = CAP;
  if (i < cn) {
    int2 p = bE[slot];
    float d = deg[p.x];
    float w = d > 0.f ? rsqrtf(d) * __int_as_float(p.y) : 0.f;
    bE[slot].y = __float_as_int(w);
  }
}

#define FMA4(A, W, V) \
  A.x = fmaf(W, V.x, A.x); A.y = fmaf(W, V.y, A.y); \
  A.z = fmaf(W, V.z, A.z); A.w = fmaf(W, V.w, A.w);

// load 4 bf16 (8B) from U row `p`, convert to f32
#define GATH(vv, p) { \
  ushort4 rw = *(const ushort4*)(sb + (size_t)(p) * 512); \
  vv.x = __uint_as_float((unsigned)rw.x << 16); \
  vv.y = __uint_as_float((unsigned)rw.y << 16); \
  vv.z = __uint_as_float((unsigned)rw.z << 16); \
  vv.w = __uint_as_float((unsigned)rw.w << 16); }

// ---- bf16-source gather: 32 lanes/node, 8 nodes/block (256 thr), 8-deep ILP ----
// PHASE 1: T1 = L_hat @ bf16(H)   (src U+128) -> U cols 256..383
// PHASE 2: T2 = 2*L_hat @ bf16(T1) - H (src U+256) -> U cols 384..511
template <int PHASE>
__global__ __launch_bounds__(256) void k_gather(
    const int* __restrict__ cnt, const int2* __restrict__ bE,
    const float* __restrict__ deg, const float* __restrict__ H,
    ushort_t* __restrict__ U) {
  int g = threadIdx.x >> 5, lane = threadIdx.x & 31;
  int node = blockIdx.x * 8 + g;
  if (node >= N_NODES) return;
  int cn = cnt[node]; if (cn > CAP) cn = CAP;
  const int2* be = bE + node * CAP;
  const ushort_t* sb = U + (PHASE == 1 ? 128 : 256) + lane * 4;
  float dc = deg[node];
  float sc = dc > 0.f ? -rsqrtf(dc) : 0.f;   // -dinv[c], factored out of the sum

  float4 z = {0.f, 0.f, 0.f, 0.f};
  float4 a0 = z, a1 = z, a2 = z, a3 = z, a4 = z, a5 = z, a6 = z, a7 = z;
  int i = 0;
  for (; i + 8 <= cn; i += 8) {
    int4e p0 = __builtin_nontemporal_load((const int4e*)(be + i));
    int4e p1 = __builtin_nontemporal_load((const int4e*)(be + i + 2));
    int4e p2 = __builtin_nontemporal_load((const int4e*)(be + i + 4));
    int4e p3 = __builtin_nontemporal_load((const int4e*)(be + i + 6));
    float4 v0, v1, v2, v3, v4, v5, v6, v7;
    GATH(v0, p0.x); GATH(v1, p0.z); GATH(v2, p1.x); GATH(v3, p1.z);
    GATH(v4, p2.x); GATH(v5, p2.z); GATH(v6, p3.x); GATH(v7, p3.z);
    FMA4(a0, __int_as_float(p0.y), v0); FMA4(a1, __int_as_float(p0.w), v1);
    FMA4(a2, __int_as_float(p1.y), v2); FMA4(a3, __int_as_float(p1.w), v3);
    FMA4(a4, __int_as_float(p2.y), v4); FMA4(a5, __int_as_float(p2.w), v5);
    FMA4(a6, __int_as_float(p3.y), v6); FMA4(a7, __int_as_float(p3.w), v7);
  }
  for (; i + 4 <= cn; i += 4) {
    int4e p0 = __builtin_nontemporal_load((const int4e*)(be + i));
    int4e p1 = __builtin_nontemporal_load((const int4e*)(be + i + 2));
    float4 v0, v1, v2, v3;
    GATH(v0, p0.x); GATH(v1, p0.z); GATH(v2, p1.x); GATH(v3, p1.z);
    FMA4(a0, __int_as_float(p0.y), v0); FMA4(a1, __int_as_float(p0.w), v1);
    FMA4(a2, __int_as_float(p1.y), v2); FMA4(a3, __int_as_float(p1.w), v3);
  }
  for (; i < cn; ++i) {
    int2 p = be[i];
    float4 v;
    GATH(v, p.x);
    FMA4(a0, __int_as_float(p.y), v);
  }
  float4 acc;
  acc.x = sc * (((a0.x + a1.x) + (a2.x + a3.x)) + ((a4.x + a5.x) + (a6.x + a7.x)));
  acc.y = sc * (((a0.y + a1.y) + (a2.y + a3.y)) + ((a4.y + a5.y) + (a6.y + a7.y)));
  acc.z = sc * (((a0.z + a1.z) + (a2.z + a3.z)) + ((a4.z + a5.z) + (a6.z + a7.z)));
  acc.w = sc * (((a0.w + a1.w) + (a2.w + a3.w)) + ((a4.w + a5.w) + (a6.w + a7.w)));

  if (PHASE == 1) {
    ushort4e u = {f2bf(acc.x), f2bf(acc.y), f2bf(acc.z), f2bf(acc.w)};
    __builtin_nontemporal_store(u, (ushort4e*)(U + (size_t)node * 512 + 256 + lane * 4));
  } else {
    float4 h = *(const float4*)(H + (size_t)node * 128 + lane * 4);
    ushort4e u = {f2bf(2.f * acc.x - h.x), f2bf(2.f * acc.y - h.y),
                  f2bf(2.f * acc.z - h.z), f2bf(2.f * acc.w - h.w)};
    __builtin_nontemporal_store(u, (ushort4e*)(U + (size_t)node * 512 + 384 + lane * 4));
  }
}

// ---- fused GEMM (R8 version): counted-vmcnt depth-2 pipeline + per-ks interleave + setprio ----
__global__ __launch_bounds__(256) void k_gemm(
    const ushort_t* __restrict__ U, const ushort_t* __restrict__ Bt,
    const float* __restrict__ bias, const float* __restrict__ C,
    float* __restrict__ out) {
  __shared__ char ldsRaw[65536];     // 2 x (16K A + 16K B); epilogue reuses as f32 tile
  char* ldsA0 = ldsRaw;
  char* ldsB0 = ldsRaw + 16384;
  char* ldsA1 = ldsRaw + 32768;
  char* ldsB1 = ldsRaw + 49152;
  float* ldsF = (float*)ldsRaw;

  const int tid = threadIdx.x;
  const int lane = tid & 63;
  const int w = tid >> 6;
  const int wr = w >> 1, wc = w & 1;
  // XCD-bijective swizzle: 3128 = 8*391; 4 n-tiles of an m-panel stay in one XCD
  const int b = blockIdx.x;
  const int g = (b & 7) * 391 + (b >> 3);
  const int m0 = (g >> 2) * 128;
  const int n0 = (g & 3) * 128;
  const int l15 = lane & 15;
  const int l4 = lane >> 4;

  auto stage_half = [&](int kt, char* la_base, char* lb_base, int h) {
    const int k0 = kt * 64;
#pragma unroll
    for (int is = 2 * h; is < 2 * h + 2; ++is) {
      int s = is * 256 + tid;
      int row = s >> 3;
      int cs = (s & 7) ^ (row & 7);        // inverse-swizzled global source chunk
      const ushort_t* ga = U + (size_t)(m0 + row) * 512 + k0 + cs * 8;
      const ushort_t* gb = Bt + (size_t)(n0 + row) * 512 + k0 + cs * 8;
      char* la = la_base + (is * 256 + (tid & 192)) * 16;   // wave-uniform base
      char* lb = lb_base + (is * 256 + (tid & 192)) * 16;
      __builtin_amdgcn_global_load_lds((const __attribute__((address_space(1))) void*)ga,
                                       (__attribute__((address_space(3))) void*)la, 16, 0, 0);
      __builtin_amdgcn_global_load_lds((const __attribute__((address_space(1))) void*)gb,
                                       (__attribute__((address_space(3))) void*)lb, 16, 0, 0);
    }
  };

  // C prefetch (epilogue operand), coalesced, issued before staging
  const int fcol = tid & 31;
  const int rbase = tid >> 5;
  float cpre[16];
#pragma unroll
  for (int half = 0; half < 2; ++half)
#pragma unroll
    for (int k = 0; k < 8; ++k) {
      int n = m0 + half * 64 + rbase + k * 8;
      int dg = (n0 >> 2) + fcol;
      cpre[half * 8 + k] = (n < N_NODES) ? C[(size_t)n * 128 + dg] : 0.f;
    }

  // loop-invariant swizzled LDS read offsets (slot independent of mi: 16%8==0)
  int offA[2][4], offB[2][4];
#pragma unroll
  for (int ks = 0; ks < 2; ++ks) {
    int slot = ((ks * 4 + l4) ^ (l15 & 7)) * 16;
#pragma unroll
    for (int i = 0; i < 4; ++i) {
      offA[ks][i] = (wr * 64 + i * 16 + l15) * 128 + slot;
      offB[ks][i] = (wc * 64 + i * 16 + l15) * 128 + slot;
    }
  }

  f32x4 acc[4][4] = {};

  stage_half(0, ldsA0, ldsB0, 0);
  stage_half(0, ldsA0, ldsB0, 1);          // 8 loads outstanding

  for (int kt = 0; kt < 8; ++kt) {
    char* curA = (kt & 1) ? ldsA1 : ldsA0;
    char* curB = (kt & 1) ? ldsB1 : ldsB0;
    char* nA = (kt & 1) ? ldsA0 : ldsA1;
    char* nB = (kt & 1) ? ldsB0 : ldsB1;
    if (kt < 7) {
      stage_half(kt + 1, nA, nB, 0);       // 4 loads -> 12 outstanding
      asm volatile("s_waitcnt vmcnt(4)" ::: "memory");  // stage(kt) landed; half1 in flight
    } else {
      asm volatile("s_waitcnt vmcnt(0)" ::: "memory");
    }
    __builtin_amdgcn_s_barrier();          // A: cur fully staged for all threads
    __builtin_amdgcn_sched_barrier(0);

    // ---- sub-phase ks=0 ----
    {
      bf16x8 af[4], bfr[4];
#pragma unroll
      for (int mi = 0; mi < 4; ++mi) af[mi] = *(const bf16x8*)(curA + offA[0][mi]);
#pragma unroll
      for (int ni = 0; ni < 4; ++ni) bfr[ni] = *(const bf16x8*)(curB + offB[0][ni]);
      asm volatile("s_waitcnt lgkmcnt(0)" ::: "memory");
      __builtin_amdgcn_sched_barrier(0);
      __builtin_amdgcn_s_setprio(1);
#pragma unroll
      for (int mi = 0; mi < 4; ++mi)
#pragma unroll
        for (int ni = 0; ni < 4; ++ni)
          acc[mi][ni] = __builtin_amdgcn_mfma_f32_16x16x32_bf16(af[mi], bfr[ni], acc[mi][ni], 0, 0, 0);
      __builtin_amdgcn_s_setprio(0);
    }
    if (kt < 7) stage_half(kt + 1, nA, nB, 1);  // 4 loads -> 8 outstanding
    // ---- sub-phase ks=1 ----
    {
      bf16x8 af[4], bfr[4];
#pragma unroll
      for (int mi = 0; mi < 4; ++mi) af[mi] = *(const bf16x8*)(curA + offA[1][mi]);
#pragma unroll
      for (int ni = 0; ni < 4; ++ni) bfr[ni] = *(const bf16x8*)(curB + offB[1][ni]);
      asm volatile("s_waitcnt lgkmcnt(0)" ::: "memory");
      __builtin_amdgcn_sched_barrier(0);
      __builtin_amdgcn_s_setprio(1);
#pragma unroll
      for (int mi = 0; mi < 4; ++mi)
#pragma unroll
        for (int ni = 0; ni < 4; ++ni)
          acc[mi][ni] = __builtin_amdgcn_mfma_f32_16x16x32_bf16(af[mi], bfr[ni], acc[mi][ni], 0, 0, 0);
      __builtin_amdgcn_s_setprio(0);
    }
    __builtin_amdgcn_s_barrier();          // B: all done reading cur; safe to overwrite
  }

  // epilogue: two row-halves through LDS, then fused LSTM elementwise
#pragma unroll
  for (int half = 0; half < 2; ++half) {
    if (wr == half) {
#pragma unroll
      for (int ni = 0; ni < 4; ++ni) {
        int col = wc * 64 + ni * 16 + l15;
        float bv = bias[n0 + col];
#pragma unroll
        for (int mi = 0; mi < 4; ++mi)
#pragma unroll
          for (int r = 0; r < 4; ++r)
            ldsF[(mi * 16 + l4 * 4 + r) * 132 + col] = acc[mi][ni][r] + bv;
      }
    }
    __syncthreads();
#pragma unroll
    for (int k = 0; k < 8; ++k) {
      int p = tid + k * 256;
      int rl = p >> 5, f = p & 31;
      int n = m0 + half * 64 + rl;
      if (n < N_NODES) {
        float4 pre = *(const float4*)&ldsF[rl * 132 + f * 4];
        int dg = (n0 >> 2) + f;
        float ig = __builtin_amdgcn_rcpf(1.f + __expf(-pre.x));
        float fg = __builtin_amdgcn_rcpf(1.f + __expf(-pre.y));
        float ec = __expf(-2.f * fabsf(pre.z));
        float tg = __builtin_copysignf((1.f - ec) * __builtin_amdgcn_rcpf(1.f + ec), pre.z);
        float og = __builtin_amdgcn_rcpf(1.f + __expf(-pre.w));
        float cOld = cpre[half * 8 + k];
        float cn = fg * cOld + ig * tg;
        float en = __expf(-2.f * fabsf(cn));
        float th = __builtin_copysignf((1.f - en) * __builtin_amdgcn_rcpf(1.f + en), cn);
        out[(size_t)n * 128 + dg] = og * th;
      }
    }
    __syncthreads();
  }
}

extern "C" void kernel_launch(void* const* d_in, const int* in_sizes, int n_in,
                              void* d_out, int out_size, void* d_ws, size_t ws_size,
                              hipStream_t stream) {
  const float* X  = (const float*)d_in[0];
  const int*   ei = (const int*)d_in[1];
  const float* ew = (const float*)d_in[2];
  const float* H  = (const float*)d_in[3];
  const float* C  = (const float*)d_in[4];
  const float* W  = (const float*)d_in[5];
  const float* b  = (const float*)d_in[6];
  const float* cW = (const float*)d_in[7];
  const float* cb = (const float*)d_in[8];
  float* out = (float*)d_out;
  char* ws = (char*)d_ws;

  float*    deg  = (float*)(ws);                 // 0.5 MB
  int*      cnt  = (int*)(ws + 0x80000);         // 0.5 MB
  int2*     bE   = (int2*)(ws + 0x100000);       // 51.2 MB CAP buckets (row, w)
  ushort_t* U    = (ushort_t*)(ws + 0x3500000);  // 100096 x 512 bf16 = 102.5 MB
  ushort_t* Bt   = (ushort_t*)(ws + 0x9700000);  // 512 KB
  float*    bias = (float*)(ws + 0x9780000);     // 2 KB

  hipMemsetAsync(ws, 0, 0x100000, stream);       // zero deg + cnt

  k_misc<<<19774, 256, 0, stream>>>(ei, ew, X, H, deg, cnt, bE, U, W, b, cW, cb, Bt, bias);
  k_scale<<<N_NODES * CAP / 256, 256, 0, stream>>>(cnt, deg, bE);
  k_gather<1><<<(N_NODES + 7) / 8, 256, 0, stream>>>(cnt, bE, deg, H, U);
  k_gather<2><<<(N_NODES + 7) / 8, 256, 0, stream>>>(cnt, bE, deg, H, U);
  k_gemm<<<3128, 256, 0, stream>>>(U, Bt, bias, C, out);
}

// Round 14
// 449.808 us; speedup vs baseline: 1.1705x; 1.0819x over previous
//
#include <hip/hip_runtime.h>

#define N_NODES 100000
#define N_EDGES 1600000
#define CAP 64

typedef unsigned short ushort_t;
typedef __attribute__((ext_vector_type(8))) short bf16x8;
typedef __attribute__((ext_vector_type(4))) float f32x4;
typedef __attribute__((ext_vector_type(4))) int int4e;
typedef __attribute__((ext_vector_type(4))) unsigned short ushort4e;

__device__ __forceinline__ unsigned short f2bf(float f) {
  unsigned int u = __float_as_uint(f);
  u = (u + 0x7FFFu + ((u >> 16) & 1u)) >> 16;
  return (unsigned short)u;
}

// ---- fused preprocessing, role-interleaved by (bid & 7) so atomic blocks and
// streaming blocks are co-resident: roles 0-1 deg atomics, 2-3 bucket scatter
// (deg-independent: stores raw ew), 4-7 pack X,H -> U bf16 + B^T/bias build ----
__global__ __launch_bounds__(256) void k_misc(
    const int* __restrict__ ei, const float* __restrict__ ew,
    const float* __restrict__ X, const float* __restrict__ H,
    float* __restrict__ deg, int* __restrict__ cnt, int2* __restrict__ bE,
    ushort_t* __restrict__ U,
    const float* __restrict__ W, const float* __restrict__ b,
    const float* __restrict__ cW, const float* __restrict__ cb,
    ushort_t* __restrict__ Bt, float* __restrict__ bias) {
  int bid = blockIdx.x;
  int role = bid & 7, q = bid >> 3;          // q < 3391
  if (role < 2) {                            // deg[row] += ew (atomic-bound)
    int e = (q * 2 + role) * 256 + threadIdx.x;
    if (e < N_EDGES) atomicAdd(&deg[ei[e]], ew[e]);
  } else if (role < 4) {                     // bucket by dst: (row, raw ew)
    int e = (q * 2 + (role - 2)) * 256 + threadIdx.x;
    if (e < N_EDGES) {
      int r = ei[e], c = ei[N_EDGES + e];
      float w = ew[e];
      int pos = atomicAdd(&cnt[c], 1);
      if (pos < CAP) bE[c * CAP + pos] = make_int2(r, __float_as_int(w));
    }
  } else {                                   // streaming: pack then bt
    int s = q * 4 + (role - 4);              // s < 13564
    if (s < 12500) {                         // pack X (cols 0-127), H (128-255)
      int i = s * 256 + threadIdx.x;         // i < 3.2M exactly
      int n = i >> 5, qq = i & 31;
      float4 x = *(const float4*)(X + (size_t)n * 128 + qq * 4);
      float4 h = *(const float4*)(H + (size_t)n * 128 + qq * 4);
      ushort4 a, bb;
      a.x = f2bf(x.x); a.y = f2bf(x.y); a.z = f2bf(x.z); a.w = f2bf(x.w);
      bb.x = f2bf(h.x); bb.y = f2bf(h.y); bb.z = f2bf(h.z); bb.w = f2bf(h.w);
      *(ushort4*)(U + (size_t)n * 512 + qq * 4) = a;
      *(ushort4*)(U + (size_t)n * 512 + 128 + qq * 4) = bb;
    } else if (s < 13524) {                  // B^T [512 j][512 k], j = d*4+g; bias
      int idx = (s - 12500) * 256 + threadIdx.x;
      int j = idx >> 9, k = idx & 511;
      int dd = j >> 2, g = j & 3;
      float v;
      if (k < 128) v = W[(g * 128 + k) * 128 + dd];
      else {
        int kk = k - 128;
        int blk = kk >> 7;
        v = cW[((g * 3 + blk) * 128 + (kk & 127)) * 128 + dd];
      }
      Bt[idx] = f2bf(v);
      if (k == 0) bias[j] = b[g * 128 + dd] + cb[g * 128 + dd];
    }
  }
}

// ---- post-pass: bE[slot].w = rsqrt(deg[row]) * raw_ew (deg now complete) ----
__global__ __launch_bounds__(256) void k_scale(
    const int* __restrict__ cnt, const float* __restrict__ deg,
    int2* __restrict__ bE) {
  int slot = blockIdx.x * 256 + threadIdx.x;     // grid covers N_NODES*CAP exactly
  int node = slot >> 6, i = slot & 63;
  int cn = cnt[node]; if (cn > CAP) cn = CAP;
  if (i < cn) {
    int2 p = bE[slot];
    float d = deg[p.x];
    float w = d > 0.f ? rsqrtf(d) * __int_as_float(p.y) : 0.f;
    bE[slot].y = __float_as_int(w);
  }
}

#define FMA4(A, W, V) \
  A.x = fmaf(W, V.x, A.x); A.y = fmaf(W, V.y, A.y); \
  A.z = fmaf(W, V.z, A.z); A.w = fmaf(W, V.w, A.w);

// load 4 bf16 (8B) from U row `p`, convert to f32
#define GATH(vv, p) { \
  ushort4 rw = *(const ushort4*)(sb + (size_t)(p) * 512); \
  vv.x = __uint_as_float((unsigned)rw.x << 16); \
  vv.y = __uint_as_float((unsigned)rw.y << 16); \
  vv.z = __uint_as_float((unsigned)rw.z << 16); \
  vv.w = __uint_as_float((unsigned)rw.w << 16); }

// ---- bf16-source gather: 32 lanes/node, 8 nodes/block (256 thr), 8-deep ILP ----
// PHASE 1: T1 = L_hat @ bf16(H)   (src U+128) -> U cols 256..383
// PHASE 2: T2 = 2*L_hat @ bf16(T1) - H (src U+256) -> U cols 384..511
template <int PHASE>
__global__ __launch_bounds__(256) void k_gather(
    const int* __restrict__ cnt, const int2* __restrict__ bE,
    const float* __restrict__ deg, const float* __restrict__ H,
    ushort_t* __restrict__ U) {
  int g = threadIdx.x >> 5, lane = threadIdx.x & 31;
  int node = blockIdx.x * 8 + g;
  if (node >= N_NODES) return;
  int cn = cnt[node]; if (cn > CAP) cn = CAP;
  const int2* be = bE + node * CAP;
  const ushort_t* sb = U + (PHASE == 1 ? 128 : 256) + lane * 4;
  float dc = deg[node];
  float sc = dc > 0.f ? -rsqrtf(dc) : 0.f;   // -dinv[c], factored out of the sum

  float4 z = {0.f, 0.f, 0.f, 0.f};
  float4 a0 = z, a1 = z, a2 = z, a3 = z, a4 = z, a5 = z, a6 = z, a7 = z;
  int i = 0;
  for (; i + 8 <= cn; i += 8) {
    int4e p0 = __builtin_nontemporal_load((const int4e*)(be + i));
    int4e p1 = __builtin_nontemporal_load((const int4e*)(be + i + 2));
    int4e p2 = __builtin_nontemporal_load((const int4e*)(be + i + 4));
    int4e p3 = __builtin_nontemporal_load((const int4e*)(be + i + 6));
    float4 v0, v1, v2, v3, v4, v5, v6, v7;
    GATH(v0, p0.x); GATH(v1, p0.z); GATH(v2, p1.x); GATH(v3, p1.z);
    GATH(v4, p2.x); GATH(v5, p2.z); GATH(v6, p3.x); GATH(v7, p3.z);
    FMA4(a0, __int_as_float(p0.y), v0); FMA4(a1, __int_as_float(p0.w), v1);
    FMA4(a2, __int_as_float(p1.y), v2); FMA4(a3, __int_as_float(p1.w), v3);
    FMA4(a4, __int_as_float(p2.y), v4); FMA4(a5, __int_as_float(p2.w), v5);
    FMA4(a6, __int_as_float(p3.y), v6); FMA4(a7, __int_as_float(p3.w), v7);
  }
  for (; i + 4 <= cn; i += 4) {
    int4e p0 = __builtin_nontemporal_load((const int4e*)(be + i));
    int4e p1 = __builtin_nontemporal_load((const int4e*)(be + i + 2));
    float4 v0, v1, v2, v3;
    GATH(v0, p0.x); GATH(v1, p0.z); GATH(v2, p1.x); GATH(v3, p1.z);
    FMA4(a0, __int_as_float(p0.y), v0); FMA4(a1, __int_as_float(p0.w), v1);
    FMA4(a2, __int_as_float(p1.y), v2); FMA4(a3, __int_as_float(p1.w), v3);
  }
  for (; i < cn; ++i) {
    int2 p = be[i];
    float4 v;
    GATH(v, p.x);
    FMA4(a0, __int_as_float(p.y), v);
  }
  float4 acc;
  acc.x = sc * (((a0.x + a1.x) + (a2.x + a3.x)) + ((a4.x + a5.x) + (a6.x + a7.x)));
  acc.y = sc * (((a0.y + a1.y) + (a2.y + a3.y)) + ((a4.y + a5.y) + (a6.y + a7.y)));
  acc.z = sc * (((a0.z + a1.z) + (a2.z + a3.z)) + ((a4.z + a5.z) + (a6.z + a7.z)));
  acc.w = sc * (((a0.w + a1.w) + (a2.w + a3.w)) + ((a4.w + a5.w) + (a6.w + a7.w)));

  if (PHASE == 1) {
    ushort4e u = {f2bf(acc.x), f2bf(acc.y), f2bf(acc.z), f2bf(acc.w)};
    __builtin_nontemporal_store(u, (ushort4e*)(U + (size_t)node * 512 + 256 + lane * 4));
  } else {
    float4 h = *(const float4*)(H + (size_t)node * 128 + lane * 4);
    ushort4e u = {f2bf(2.f * acc.x - h.x), f2bf(2.f * acc.y - h.y),
                  f2bf(2.f * acc.z - h.z), f2bf(2.f * acc.w - h.w)};
    __builtin_nontemporal_store(u, (ushort4e*)(U + (size_t)node * 512 + 384 + lane * 4));
  }
}

// ---- fused GEMM (R8 version): counted-vmcnt depth-2 pipeline + per-ks interleave + setprio ----
__global__ __launch_bounds__(256) void k_gemm(
    const ushort_t* __restrict__ U, const ushort_t* __restrict__ Bt,
    const float* __restrict__ bias, const float* __restrict__ C,
    float* __restrict__ out) {
  __shared__ char ldsRaw[65536];     // 2 x (16K A + 16K B); epilogue reuses as f32 tile
  char* ldsA0 = ldsRaw;
  char* ldsB0 = ldsRaw + 16384;
  char* ldsA1 = ldsRaw + 32768;
  char* ldsB1 = ldsRaw + 49152;
  float* ldsF = (float*)ldsRaw;

  const int tid = threadIdx.x;
  const int lane = tid & 63;
  const int w = tid >> 6;
  const int wr = w >> 1, wc = w & 1;
  // XCD-bijective swizzle: 3128 = 8*391; 4 n-tiles of an m-panel stay in one XCD
  const int b = blockIdx.x;
  const int g = (b & 7) * 391 + (b >> 3);
  const int m0 = (g >> 2) * 128;
  const int n0 = (g & 3) * 128;
  const int l15 = lane & 15;
  const int l4 = lane >> 4;

  auto stage_half = [&](int kt, char* la_base, char* lb_base, int h) {
    const int k0 = kt * 64;
#pragma unroll
    for (int is = 2 * h; is < 2 * h + 2; ++is) {
      int s = is * 256 + tid;
      int row = s >> 3;
      int cs = (s & 7) ^ (row & 7);        // inverse-swizzled global source chunk
      const ushort_t* ga = U + (size_t)(m0 + row) * 512 + k0 + cs * 8;
      const ushort_t* gb = Bt + (size_t)(n0 + row) * 512 + k0 + cs * 8;
      char* la = la_base + (is * 256 + (tid & 192)) * 16;   // wave-uniform base
      char* lb = lb_base + (is * 256 + (tid & 192)) * 16;
      __builtin_amdgcn_global_load_lds((const __attribute__((address_space(1))) void*)ga,
                                       (__attribute__((address_space(3))) void*)la, 16, 0, 0);
      __builtin_amdgcn_global_load_lds((const __attribute__((address_space(1))) void*)gb,
                                       (__attribute__((address_space(3))) void*)lb, 16, 0, 0);
    }
  };

  // C prefetch (epilogue operand), nontemporal (single-touch, keep out of L2)
  const int fcol = tid & 31;
  const int rbase = tid >> 5;
  float cpre[16];
#pragma unroll
  for (int half = 0; half < 2; ++half)
#pragma unroll
    for (int k = 0; k < 8; ++k) {
      int n = m0 + half * 64 + rbase + k * 8;
      int dg = (n0 >> 2) + fcol;
      cpre[half * 8 + k] = (n < N_NODES)
          ? __builtin_nontemporal_load(C + (size_t)n * 128 + dg) : 0.f;
    }

  // loop-invariant swizzled LDS read offsets (slot independent of mi: 16%8==0)
  int offA[2][4], offB[2][4];
#pragma unroll
  for (int ks = 0; ks < 2; ++ks) {
    int slot = ((ks * 4 + l4) ^ (l15 & 7)) * 16;
#pragma unroll
    for (int i = 0; i < 4; ++i) {
      offA[ks][i] = (wr * 64 + i * 16 + l15) * 128 + slot;
      offB[ks][i] = (wc * 64 + i * 16 + l15) * 128 + slot;
    }
  }

  f32x4 acc[4][4] = {};

  stage_half(0, ldsA0, ldsB0, 0);
  stage_half(0, ldsA0, ldsB0, 1);          // 8 loads outstanding

  for (int kt = 0; kt < 8; ++kt) {
    char* curA = (kt & 1) ? ldsA1 : ldsA0;
    char* curB = (kt & 1) ? ldsB1 : ldsB0;
    char* nA = (kt & 1) ? ldsA0 : ldsA1;
    char* nB = (kt & 1) ? ldsB0 : ldsB1;
    if (kt < 7) {
      stage_half(kt + 1, nA, nB, 0);       // 4 loads -> 12 outstanding
      asm volatile("s_waitcnt vmcnt(4)" ::: "memory");  // stage(kt) landed; half1 in flight
    } else {
      asm volatile("s_waitcnt vmcnt(0)" ::: "memory");
    }
    __builtin_amdgcn_s_barrier();          // A: cur fully staged for all threads
    __builtin_amdgcn_sched_barrier(0);

    // ---- sub-phase ks=0 ----
    {
      bf16x8 af[4], bfr[4];
#pragma unroll
      for (int mi = 0; mi < 4; ++mi) af[mi] = *(const bf16x8*)(curA + offA[0][mi]);
#pragma unroll
      for (int ni = 0; ni < 4; ++ni) bfr[ni] = *(const bf16x8*)(curB + offB[0][ni]);
      asm volatile("s_waitcnt lgkmcnt(0)" ::: "memory");
      __builtin_amdgcn_sched_barrier(0);
      __builtin_amdgcn_s_setprio(1);
#pragma unroll
      for (int mi = 0; mi < 4; ++mi)
#pragma unroll
        for (int ni = 0; ni < 4; ++ni)
          acc[mi][ni] = __builtin_amdgcn_mfma_f32_16x16x32_bf16(af[mi], bfr[ni], acc[mi][ni], 0, 0, 0);
      __builtin_amdgcn_s_setprio(0);
    }
    if (kt < 7) stage_half(kt + 1, nA, nB, 1);  // 4 loads -> 8 outstanding
    // ---- sub-phase ks=1 ----
    {
      bf16x8 af[4], bfr[4];
#pragma unroll
      for (int mi = 0; mi < 4; ++mi) af[mi] = *(const bf16x8*)(curA + offA[1][mi]);
#pragma unroll
      for (int ni = 0; ni < 4; ++ni) bfr[ni] = *(const bf16x8*)(curB + offB[1][ni]);
      asm volatile("s_waitcnt lgkmcnt(0)" ::: "memory");
      __builtin_amdgcn_sched_barrier(0);
      __builtin_amdgcn_s_setprio(1);
#pragma unroll
      for (int mi = 0; mi < 4; ++mi)
#pragma unroll
        for (int ni = 0; ni < 4; ++ni)
          acc[mi][ni] = __builtin_amdgcn_mfma_f32_16x16x32_bf16(af[mi], bfr[ni], acc[mi][ni], 0, 0, 0);
      __builtin_amdgcn_s_setprio(0);
    }
    __builtin_amdgcn_s_barrier();          // B: all done reading cur; safe to overwrite
  }

  // epilogue: two row-halves through LDS, then fused LSTM elementwise
#pragma unroll
  for (int half = 0; half < 2; ++half) {
    if (wr == half) {
#pragma unroll
      for (int ni = 0; ni < 4; ++ni) {
        int col = wc * 64 + ni * 16 + l15;
        float bv = bias[n0 + col];
#pragma unroll
        for (int mi = 0; mi < 4; ++mi)
#pragma unroll
          for (int r = 0; r < 4; ++r)
            ldsF[(mi * 16 + l4 * 4 + r) * 132 + col] = acc[mi][ni][r] + bv;
      }
    }
    __syncthreads();
#pragma unroll
    for (int k = 0; k < 8; ++k) {
      int p = tid + k * 256;
      int rl = p >> 5, f = p & 31;
      int n = m0 + half * 64 + rl;
      if (n < N_NODES) {
        float4 pre = *(const float4*)&ldsF[rl * 132 + f * 4];
        int dg = (n0 >> 2) + f;
        float ig = __builtin_amdgcn_rcpf(1.f + __expf(-pre.x));
        float fg = __builtin_amdgcn_rcpf(1.f + __expf(-pre.y));
        float ec = __expf(-2.f * fabsf(pre.z));
        float tg = __builtin_copysignf((1.f - ec) * __builtin_amdgcn_rcpf(1.f + ec), pre.z);
        float og = __builtin_amdgcn_rcpf(1.f + __expf(-pre.w));
        float cOld = cpre[half * 8 + k];
        float cn = fg * cOld + ig * tg;
        float en = __expf(-2.f * fabsf(cn));
        float th = __builtin_copysignf((1.f - en) * __builtin_amdgcn_rcpf(1.f + en), cn);
        __builtin_nontemporal_store(og * th, out + (size_t)n * 128 + dg);
      }
    }
    __syncthreads();
  }
}

extern "C" void kernel_launch(void* const* d_in, const int* in_sizes, int n_in,
                              void* d_out, int out_size, void* d_ws, size_t ws_size,
                              hipStream_t stream) {
  const float* X  = (const float*)d_in[0];
  const int*   ei = (const int*)d_in[1];
  const float* ew = (const float*)d_in[2];
  const float* H  = (const float*)d_in[3];
  const float* C  = (const float*)d_in[4];
  const float* W  = (const float*)d_in[5];
  const float* b  = (const float*)d_in[6];
  const float* cW = (const float*)d_in[7];
  const float* cb = (const float*)d_in[8];
  float* out = (float*)d_out;
  char* ws = (char*)d_ws;

  float*    deg  = (float*)(ws);                 // 0.5 MB
  int*      cnt  = (int*)(ws + 0x80000);         // 0.5 MB
  int2*     bE   = (int2*)(ws + 0x100000);       // 51.2 MB CAP buckets (row, w)
  ushort_t* U    = (ushort_t*)(ws + 0x3500000);  // 100096 x 512 bf16 = 102.5 MB
  ushort_t* Bt   = (ushort_t*)(ws + 0x9700000);  // 512 KB
  float*    bias = (float*)(ws + 0x9780000);     // 2 KB

  hipMemsetAsync(ws, 0, 0x100000, stream);       // zero deg + cnt

  k_misc<<<27128, 256, 0, stream>>>(ei, ew, X, H, deg, cnt, bE, U, W, b, cW, cb, Bt, bias);
  k_scale<<<N_NODES * CAP / 256, 256, 0, stream>>>(cnt, deg, bE);
  k_gather<1><<<(N_NODES + 7) / 8, 256, 0, stream>>>(cnt, bE, deg, H, U);
  k_gather<2><<<(N_NODES + 7) / 8, 256, 0, stream>>>(cnt, bE, deg, H, U);
  k_gemm<<<3128, 256, 0, stream>>>(U, Bt, bias, C, out);
}

// Round 15
// 424.270 us; speedup vs baseline: 1.2409x; 1.0602x over previous
//
#include <hip/hip_runtime.h>

#define N_NODES 100000
#define N_EDGES 1600000
#define CAP 64

typedef unsigned short ushort_t;
typedef __attribute__((ext_vector_type(8))) short bf16x8;
typedef __attribute__((ext_vector_type(4))) float f32x4;
typedef __attribute__((ext_vector_type(4))) int int4e;
typedef __attribute__((ext_vector_type(8))) unsigned short ushort8e;

__device__ __forceinline__ unsigned short f2bf(float f) {
  unsigned int u = __float_as_uint(f);
  u = (u + 0x7FFFu + ((u >> 16) & 1u)) >> 16;
  return (unsigned short)u;
}

// ---- fused preprocessing, role-interleaved by (bid & 7): roles 0-1 deg atomics
// (each role -> its own deg copy; role == likely XCD -> L2-local lines),
// roles 2-3 bucket scatter (raw ew), 4-7 pack X,H -> U bf16 + B^T/bias ----
__global__ __launch_bounds__(256) void k_misc(
    const int* __restrict__ ei, const float* __restrict__ ew,
    const float* __restrict__ X, const float* __restrict__ H,
    float* __restrict__ degc0, float* __restrict__ degc1,
    int* __restrict__ cnt, int2* __restrict__ bE,
    ushort_t* __restrict__ U,
    const float* __restrict__ W, const float* __restrict__ b,
    const float* __restrict__ cW, const float* __restrict__ cb,
    ushort_t* __restrict__ Bt, float* __restrict__ bias) {
  int bid = blockIdx.x;
  int role = bid & 7, q = bid >> 3;          // q < 3391
  if (role < 2) {                            // deg atomics into per-role copy
    int e = (q * 2 + role) * 256 + threadIdx.x;
    if (e < N_EDGES) {
      float* dg = role ? degc1 : degc0;
      atomicAdd(&dg[ei[e]], ew[e]);
    }
  } else if (role < 4) {                     // bucket by dst: (row, raw ew)
    int e = (q * 2 + (role - 2)) * 256 + threadIdx.x;
    if (e < N_EDGES) {
      int r = ei[e], c = ei[N_EDGES + e];
      float w = ew[e];
      int pos = atomicAdd(&cnt[c], 1);
      if (pos < CAP) bE[c * CAP + pos] = make_int2(r, __float_as_int(w));
    }
  } else {                                   // streaming: pack then bt
    int s = q * 4 + (role - 4);              // s < 13564
    if (s < 12500) {                         // pack X (cols 0-127), H (128-255)
      int i = s * 256 + threadIdx.x;         // i < 3.2M exactly
      int n = i >> 5, qq = i & 31;
      float4 x = *(const float4*)(X + (size_t)n * 128 + qq * 4);
      float4 h = *(const float4*)(H + (size_t)n * 128 + qq * 4);
      ushort4 a, bb;
      a.x = f2bf(x.x); a.y = f2bf(x.y); a.z = f2bf(x.z); a.w = f2bf(x.w);
      bb.x = f2bf(h.x); bb.y = f2bf(h.y); bb.z = f2bf(h.z); bb.w = f2bf(h.w);
      *(ushort4*)(U + (size_t)n * 512 + qq * 4) = a;
      *(ushort4*)(U + (size_t)n * 512 + 128 + qq * 4) = bb;
    } else if (s < 13524) {                  // B^T [512 j][512 k], j = d*4+g; bias
      int idx = (s - 12500) * 256 + threadIdx.x;
      int j = idx >> 9, k = idx & 511;
      int dd = j >> 2, g = j & 3;
      float v;
      if (k < 128) v = W[(g * 128 + k) * 128 + dd];
      else {
        int kk = k - 128;
        int blk = kk >> 7;
        v = cW[((g * 3 + blk) * 128 + (kk & 127)) * 128 + dd];
      }
      Bt[idx] = f2bf(v);
      if (k == 0) bias[j] = b[g * 128 + dd] + cb[g * 128 + dd];
    }
  }
}

// ---- deg = degc0 + degc1 ----
__global__ __launch_bounds__(256) void k_sumdeg(
    const float* __restrict__ degc0, const float* __restrict__ degc1,
    float* __restrict__ deg) {
  int i = blockIdx.x * 256 + threadIdx.x;
  deg[i] = degc0[i] + degc1[i];
}

// ---- post-pass: bE[slot].w = rsqrt(deg[row]) * raw_ew (deg now complete) ----
__global__ __launch_bounds__(256) void k_scale(
    const int* __restrict__ cnt, const float* __restrict__ deg,
    int2* __restrict__ bE) {
  int slot = blockIdx.x * 256 + threadIdx.x;     // grid covers N_NODES*CAP exactly
  int node = slot >> 6, i = slot & 63;
  int cn = cnt[node]; if (cn > CAP) cn = CAP;
  if (i < cn) {
    int2 p = bE[slot];
    float d = deg[p.x];
    float w = d > 0.f ? rsqrtf(d) * __int_as_float(p.y) : 0.f;
    bE[slot].y = __float_as_int(w);
  }
}

// FMA of one bf16-packed row (int4e = 8 bf16) into 8-col accumulator A
#define FMA8(A, Wt, R) { \
  A[0] = fmaf(Wt, __uint_as_float((unsigned)R.x << 16), A[0]); \
  A[1] = fmaf(Wt, __uint_as_float((unsigned)R.x & 0xffff0000u), A[1]); \
  A[2] = fmaf(Wt, __uint_as_float((unsigned)R.y << 16), A[2]); \
  A[3] = fmaf(Wt, __uint_as_float((unsigned)R.y & 0xffff0000u), A[3]); \
  A[4] = fmaf(Wt, __uint_as_float((unsigned)R.z << 16), A[4]); \
  A[5] = fmaf(Wt, __uint_as_float((unsigned)R.z & 0xffff0000u), A[5]); \
  A[6] = fmaf(Wt, __uint_as_float((unsigned)R.w << 16), A[6]); \
  A[7] = fmaf(Wt, __uint_as_float((unsigned)R.w & 0xffff0000u), A[7]); }

// ---- bf16-source gather: 16 lanes/node (16B each), 16 nodes/block, 8-deep ILP ----
// PHASE 1: T1 = L_hat @ bf16(H)   (src U+128) -> U cols 256..383
// PHASE 2: T2 = 2*L_hat @ bf16(T1) - H (src U+256) -> U cols 384..511
template <int PHASE>
__global__ __launch_bounds__(256) void k_gather(
    const int* __restrict__ cnt, const int2* __restrict__ bE,
    const float* __restrict__ deg, const float* __restrict__ H,
    ushort_t* __restrict__ U) {
  int g = threadIdx.x >> 4, lane = threadIdx.x & 15;
  int node = blockIdx.x * 16 + g;
  if (node >= N_NODES) return;
  int cn = cnt[node]; if (cn > CAP) cn = CAP;
  const int2* be = bE + node * CAP;
  const ushort_t* sb = U + (PHASE == 1 ? 128 : 256) + lane * 8;
  float dc = deg[node];
  float sc = dc > 0.f ? -rsqrtf(dc) : 0.f;   // -dinv[c], factored out of the sum

  float a0[8] = {}, a1[8] = {}, a2[8] = {}, a3[8] = {};
  float a4[8] = {}, a5[8] = {}, a6[8] = {}, a7[8] = {};
  int i = 0;
  for (; i + 8 <= cn; i += 8) {
    int4e p0 = __builtin_nontemporal_load((const int4e*)(be + i));
    int4e p1 = __builtin_nontemporal_load((const int4e*)(be + i + 2));
    int4e p2 = __builtin_nontemporal_load((const int4e*)(be + i + 4));
    int4e p3 = __builtin_nontemporal_load((const int4e*)(be + i + 6));
    int4e r0 = *(const int4e*)(sb + (size_t)p0.x * 512);
    int4e r1 = *(const int4e*)(sb + (size_t)p0.z * 512);
    int4e r2 = *(const int4e*)(sb + (size_t)p1.x * 512);
    int4e r3 = *(const int4e*)(sb + (size_t)p1.z * 512);
    int4e r4 = *(const int4e*)(sb + (size_t)p2.x * 512);
    int4e r5 = *(const int4e*)(sb + (size_t)p2.z * 512);
    int4e r6 = *(const int4e*)(sb + (size_t)p3.x * 512);
    int4e r7 = *(const int4e*)(sb + (size_t)p3.z * 512);
    FMA8(a0, __int_as_float(p0.y), r0); FMA8(a1, __int_as_float(p0.w), r1);
    FMA8(a2, __int_as_float(p1.y), r2); FMA8(a3, __int_as_float(p1.w), r3);
    FMA8(a4, __int_as_float(p2.y), r4); FMA8(a5, __int_as_float(p2.w), r5);
    FMA8(a6, __int_as_float(p3.y), r6); FMA8(a7, __int_as_float(p3.w), r7);
  }
  for (; i + 4 <= cn; i += 4) {
    int4e p0 = __builtin_nontemporal_load((const int4e*)(be + i));
    int4e p1 = __builtin_nontemporal_load((const int4e*)(be + i + 2));
    int4e r0 = *(const int4e*)(sb + (size_t)p0.x * 512);
    int4e r1 = *(const int4e*)(sb + (size_t)p0.z * 512);
    int4e r2 = *(const int4e*)(sb + (size_t)p1.x * 512);
    int4e r3 = *(const int4e*)(sb + (size_t)p1.z * 512);
    FMA8(a0, __int_as_float(p0.y), r0); FMA8(a1, __int_as_float(p0.w), r1);
    FMA8(a2, __int_as_float(p1.y), r2); FMA8(a3, __int_as_float(p1.w), r3);
  }
  for (; i < cn; ++i) {
    int2 p = be[i];
    int4e r0 = *(const int4e*)(sb + (size_t)p.x * 512);
    FMA8(a0, __int_as_float(p.y), r0);
  }
  float o[8];
#pragma unroll
  for (int j = 0; j < 8; ++j)
    o[j] = sc * (((a0[j] + a1[j]) + (a2[j] + a3[j])) +
                 ((a4[j] + a5[j]) + (a6[j] + a7[j])));

  if (PHASE == 1) {
    ushort8e u;
#pragma unroll
    for (int j = 0; j < 8; ++j) u[j] = f2bf(o[j]);
    __builtin_nontemporal_store(u, (ushort8e*)(U + (size_t)node * 512 + 256 + lane * 8));
  } else {
    float4 hlo = *(const float4*)(H + (size_t)node * 128 + lane * 8);
    float4 hhi = *(const float4*)(H + (size_t)node * 128 + lane * 8 + 4);
    ushort8e u;
    u[0] = f2bf(2.f * o[0] - hlo.x); u[1] = f2bf(2.f * o[1] - hlo.y);
    u[2] = f2bf(2.f * o[2] - hlo.z); u[3] = f2bf(2.f * o[3] - hlo.w);
    u[4] = f2bf(2.f * o[4] - hhi.x); u[5] = f2bf(2.f * o[5] - hhi.y);
    u[6] = f2bf(2.f * o[6] - hhi.z); u[7] = f2bf(2.f * o[7] - hhi.w);
    __builtin_nontemporal_store(u, (ushort8e*)(U + (size_t)node * 512 + 384 + lane * 8));
  }
}

// ---- fused GEMM (R8 version): counted-vmcnt depth-2 pipeline + per-ks interleave + setprio ----
__global__ __launch_bounds__(256) void k_gemm(
    const ushort_t* __restrict__ U, const ushort_t* __restrict__ Bt,
    const float* __restrict__ bias, const float* __restrict__ C,
    float* __restrict__ out) {
  __shared__ char ldsRaw[65536];     // 2 x (16K A + 16K B); epilogue reuses as f32 tile
  char* ldsA0 = ldsRaw;
  char* ldsB0 = ldsRaw + 16384;
  char* ldsA1 = ldsRaw + 32768;
  char* ldsB1 = ldsRaw + 49152;
  float* ldsF = (float*)ldsRaw;

  const int tid = threadIdx.x;
  const int lane = tid & 63;
  const int w = tid >> 6;
  const int wr = w >> 1, wc = w & 1;
  // XCD-bijective swizzle: 3128 = 8*391; 4 n-tiles of an m-panel stay in one XCD
  const int b = blockIdx.x;
  const int g = (b & 7) * 391 + (b >> 3);
  const int m0 = (g >> 2) * 128;
  const int n0 = (g & 3) * 128;
  const int l15 = lane & 15;
  const int l4 = lane >> 4;

  auto stage_half = [&](int kt, char* la_base, char* lb_base, int h) {
    const int k0 = kt * 64;
#pragma unroll
    for (int is = 2 * h; is < 2 * h + 2; ++is) {
      int s = is * 256 + tid;
      int row = s >> 3;
      int cs = (s & 7) ^ (row & 7);        // inverse-swizzled global source chunk
      const ushort_t* ga = U + (size_t)(m0 + row) * 512 + k0 + cs * 8;
      const ushort_t* gb = Bt + (size_t)(n0 + row) * 512 + k0 + cs * 8;
      char* la = la_base + (is * 256 + (tid & 192)) * 16;   // wave-uniform base
      char* lb = lb_base + (is * 256 + (tid & 192)) * 16;
      __builtin_amdgcn_global_load_lds((const __attribute__((address_space(1))) void*)ga,
                                       (__attribute__((address_space(3))) void*)la, 16, 0, 0);
      __builtin_amdgcn_global_load_lds((const __attribute__((address_space(1))) void*)gb,
                                       (__attribute__((address_space(3))) void*)lb, 16, 0, 0);
    }
  };

  // C prefetch (epilogue operand), nontemporal (single-touch, keep out of L2)
  const int fcol = tid & 31;
  const int rbase = tid >> 5;
  float cpre[16];
#pragma unroll
  for (int half = 0; half < 2; ++half)
#pragma unroll
    for (int k = 0; k < 8; ++k) {
      int n = m0 + half * 64 + rbase + k * 8;
      int dg = (n0 >> 2) + fcol;
      cpre[half * 8 + k] = (n < N_NODES)
          ? __builtin_nontemporal_load(C + (size_t)n * 128 + dg) : 0.f;
    }

  // loop-invariant swizzled LDS read offsets (slot independent of mi: 16%8==0)
  int offA[2][4], offB[2][4];
#pragma unroll
  for (int ks = 0; ks < 2; ++ks) {
    int slot = ((ks * 4 + l4) ^ (l15 & 7)) * 16;
#pragma unroll
    for (int i = 0; i < 4; ++i) {
      offA[ks][i] = (wr * 64 + i * 16 + l15) * 128 + slot;
      offB[ks][i] = (wc * 64 + i * 16 + l15) * 128 + slot;
    }
  }

  f32x4 acc[4][4] = {};

  stage_half(0, ldsA0, ldsB0, 0);
  stage_half(0, ldsA0, ldsB0, 1);          // 8 loads outstanding

  for (int kt = 0; kt < 8; ++kt) {
    char* curA = (kt & 1) ? ldsA1 : ldsA0;
    char* curB = (kt & 1) ? ldsB1 : ldsB0;
    char* nA = (kt & 1) ? ldsA0 : ldsA1;
    char* nB = (kt & 1) ? ldsB0 : ldsB1;
    if (kt < 7) {
      stage_half(kt + 1, nA, nB, 0);       // 4 loads -> 12 outstanding
      asm volatile("s_waitcnt vmcnt(4)" ::: "memory");  // stage(kt) landed; half1 in flight
    } else {
      asm volatile("s_waitcnt vmcnt(0)" ::: "memory");
    }
    __builtin_amdgcn_s_barrier();          // A: cur fully staged for all threads
    __builtin_amdgcn_sched_barrier(0);

    // ---- sub-phase ks=0 ----
    {
      bf16x8 af[4], bfr[4];
#pragma unroll
      for (int mi = 0; mi < 4; ++mi) af[mi] = *(const bf16x8*)(curA + offA[0][mi]);
#pragma unroll
      for (int ni = 0; ni < 4; ++ni) bfr[ni] = *(const bf16x8*)(curB + offB[0][ni]);
      asm volatile("s_waitcnt lgkmcnt(0)" ::: "memory");
      __builtin_amdgcn_sched_barrier(0);
      __builtin_amdgcn_s_setprio(1);
#pragma unroll
      for (int mi = 0; mi < 4; ++mi)
#pragma unroll
        for (int ni = 0; ni < 4; ++ni)
          acc[mi][ni] = __builtin_amdgcn_mfma_f32_16x16x32_bf16(af[mi], bfr[ni], acc[mi][ni], 0, 0, 0);
      __builtin_amdgcn_s_setprio(0);
    }
    if (kt < 7) stage_half(kt + 1, nA, nB, 1);  // 4 loads -> 8 outstanding
    // ---- sub-phase ks=1 ----
    {
      bf16x8 af[4], bfr[4];
#pragma unroll
      for (int mi = 0; mi < 4; ++mi) af[mi] = *(const bf16x8*)(curA + offA[1][mi]);
#pragma unroll
      for (int ni = 0; ni < 4; ++ni) bfr[ni] = *(const bf16x8*)(curB + offB[1][ni]);
      asm volatile("s_waitcnt lgkmcnt(0)" ::: "memory");
      __builtin_amdgcn_sched_barrier(0);
      __builtin_amdgcn_s_setprio(1);
#pragma unroll
      for (int mi = 0; mi < 4; ++mi)
#pragma unroll
        for (int ni = 0; ni < 4; ++ni)
          acc[mi][ni] = __builtin_amdgcn_mfma_f32_16x16x32_bf16(af[mi], bfr[ni], acc[mi][ni], 0, 0, 0);
      __builtin_amdgcn_s_setprio(0);
    }
    __builtin_amdgcn_s_barrier();          // B: all done reading cur; safe to overwrite
  }

  // epilogue: two row-halves through LDS, then fused LSTM elementwise
#pragma unroll
  for (int half = 0; half < 2; ++half) {
    if (wr == half) {
#pragma unroll
      for (int ni = 0; ni < 4; ++ni) {
        int col = wc * 64 + ni * 16 + l15;
        float bv = bias[n0 + col];
#pragma unroll
        for (int mi = 0; mi < 4; ++mi)
#pragma unroll
          for (int r = 0; r < 4; ++r)
            ldsF[(mi * 16 + l4 * 4 + r) * 132 + col] = acc[mi][ni][r] + bv;
      }
    }
    __syncthreads();
#pragma unroll
    for (int k = 0; k < 8; ++k) {
      int p = tid + k * 256;
      int rl = p >> 5, f = p & 31;
      int n = m0 + half * 64 + rl;
      if (n < N_NODES) {
        float4 pre = *(const float4*)&ldsF[rl * 132 + f * 4];
        int dg = (n0 >> 2) + f;
        float ig = __builtin_amdgcn_rcpf(1.f + __expf(-pre.x));
        float fg = __builtin_amdgcn_rcpf(1.f + __expf(-pre.y));
        float ec = __expf(-2.f * fabsf(pre.z));
        float tg = __builtin_copysignf((1.f - ec) * __builtin_amdgcn_rcpf(1.f + ec), pre.z);
        float og = __builtin_amdgcn_rcpf(1.f + __expf(-pre.w));
        float cOld = cpre[half * 8 + k];
        float cn = fg * cOld + ig * tg;
        float en = __expf(-2.f * fabsf(cn));
        float th = __builtin_copysignf((1.f - en) * __builtin_amdgcn_rcpf(1.f + en), cn);
        __builtin_nontemporal_store(og * th, out + (size_t)n * 128 + dg);
      }
    }
    __syncthreads();
  }
}

extern "C" void kernel_launch(void* const* d_in, const int* in_sizes, int n_in,
                              void* d_out, int out_size, void* d_ws, size_t ws_size,
                              hipStream_t stream) {
  const float* X  = (const float*)d_in[0];
  const int*   ei = (const int*)d_in[1];
  const float* ew = (const float*)d_in[2];
  const float* H  = (const float*)d_in[3];
  const float* C  = (const float*)d_in[4];
  const float* W  = (const float*)d_in[5];
  const float* b  = (const float*)d_in[6];
  const float* cW = (const float*)d_in[7];
  const float* cb = (const float*)d_in[8];
  float* out = (float*)d_out;
  char* ws = (char*)d_ws;

  float*    degc0 = (float*)(ws);                 // 0.5 MB (per-role deg copy)
  float*    degc1 = (float*)(ws + 0x80000);       // 0.5 MB
  float*    deg   = (float*)(ws + 0x100000);      // 0.5 MB (summed)
  int*      cnt   = (int*)(ws + 0x180000);        // 0.5 MB
  int2*     bE    = (int2*)(ws + 0x200000);       // 51.2 MB CAP buckets (row, w)
  ushort_t* U     = (ushort_t*)(ws + 0x3600000);  // 100096 x 512 bf16 = 102.5 MB
  ushort_t* Bt    = (ushort_t*)(ws + 0x9800000);  // 512 KB
  float*    bias  = (float*)(ws + 0x9880000);     // 2 KB

  hipMemsetAsync(ws, 0, 0x200000, stream);        // zero degc0/degc1/deg/cnt

  k_misc<<<27128, 256, 0, stream>>>(ei, ew, X, H, degc0, degc1, cnt, bE, U,
                                    W, b, cW, cb, Bt, bias);
  k_sumdeg<<<392, 256, 0, stream>>>(degc0, degc1, deg);
  k_scale<<<N_NODES * CAP / 256, 256, 0, stream>>>(cnt, deg, bE);
  k_gather<1><<<(N_NODES + 15) / 16, 256, 0, stream>>>(cnt, bE, deg, H, U);
  k_gather<2><<<(N_NODES + 15) / 16, 256, 0, stream>>>(cnt, bE, deg, H, U);
  k_gemm<<<3128, 256, 0, stream>>>(U, Bt, bias, C, out);
}

// Round 16
// 401.524 us; speedup vs baseline: 1.3112x; 1.0567x over previous
//
#include <hip/hip_runtime.h>

#define N_NODES 100000
#define N_EDGES 1600000
#define CAP 64

typedef unsigned short ushort_t;
typedef __attribute__((ext_vector_type(8))) short bf16x8;
typedef __attribute__((ext_vector_type(4))) float f32x4;
typedef __attribute__((ext_vector_type(4))) int int4e;
typedef __attribute__((ext_vector_type(8))) unsigned short ushort8e;

__device__ __forceinline__ unsigned short f2bf(float f) {
  unsigned int u = __float_as_uint(f);
  u = (u + 0x7FFFu + ((u >> 16) & 1u)) >> 16;
  return (unsigned short)u;
}

// ---- fused preprocessing, role-interleaved by (bid & 7): roles 0-1 deg atomics,
// roles 2-3 bucket scatter (raw ew), 4-7 pack X,H -> U bf16 + B^T/bias ----
__global__ __launch_bounds__(256) void k_misc(
    const int* __restrict__ ei, const float* __restrict__ ew,
    const float* __restrict__ X, const float* __restrict__ H,
    float* __restrict__ deg, int* __restrict__ cnt, int2* __restrict__ bE,
    ushort_t* __restrict__ U,
    const float* __restrict__ W, const float* __restrict__ b,
    const float* __restrict__ cW, const float* __restrict__ cb,
    ushort_t* __restrict__ Bt, float* __restrict__ bias) {
  int bid = blockIdx.x;
  int role = bid & 7, q = bid >> 3;          // q < 3391
  if (role < 2) {                            // deg atomics
    int e = (q * 2 + role) * 256 + threadIdx.x;
    if (e < N_EDGES) atomicAdd(&deg[ei[e]], ew[e]);
  } else if (role < 4) {                     // bucket by dst: (row, raw ew)
    int e = (q * 2 + (role - 2)) * 256 + threadIdx.x;
    if (e < N_EDGES) {
      int r = ei[e], c = ei[N_EDGES + e];
      float w = ew[e];
      int pos = atomicAdd(&cnt[c], 1);
      if (pos < CAP) bE[c * CAP + pos] = make_int2(r, __float_as_int(w));
    }
  } else {                                   // streaming: pack then bt
    int s = q * 4 + (role - 4);              // s < 13564
    if (s < 12500) {                         // pack X (cols 0-127), H (128-255)
      int i = s * 256 + threadIdx.x;         // i < 3.2M exactly
      int n = i >> 5, qq = i & 31;
      float4 x = *(const float4*)(X + (size_t)n * 128 + qq * 4);
      float4 h = *(const float4*)(H + (size_t)n * 128 + qq * 4);
      ushort4 a, bb;
      a.x = f2bf(x.x); a.y = f2bf(x.y); a.z = f2bf(x.z); a.w = f2bf(x.w);
      bb.x = f2bf(h.x); bb.y = f2bf(h.y); bb.z = f2bf(h.z); bb.w = f2bf(h.w);
      *(ushort4*)(U + (size_t)n * 512 + qq * 4) = a;
      *(ushort4*)(U + (size_t)n * 512 + 128 + qq * 4) = bb;
    } else if (s < 13524) {                  // B^T [512 j][512 k], j = d*4+g; bias
      int idx = (s - 12500) * 256 + threadIdx.x;
      int j = idx >> 9, k = idx & 511;
      int dd = j >> 2, g = j & 3;
      float v;
      if (k < 128) v = W[(g * 128 + k) * 128 + dd];
      else {
        int kk = k - 128;
        int blk = kk >> 7;
        v = cW[((g * 3 + blk) * 128 + (kk & 127)) * 128 + dd];
      }
      Bt[idx] = f2bf(v);
      if (k == 0) bias[j] = b[g * 128 + dd] + cb[g * 128 + dd];
    }
  }
}

// ---- post-pass: bE[slot].w = rsqrt(deg[row]) * raw_ew (deg now complete) ----
__global__ __launch_bounds__(256) void k_scale(
    const int* __restrict__ cnt, const float* __restrict__ deg,
    int2* __restrict__ bE) {
  int slot = blockIdx.x * 256 + threadIdx.x;     // grid covers N_NODES*CAP exactly
  int node = slot >> 6, i = slot & 63;
  int cn = cnt[node]; if (cn > CAP) cn = CAP;
  if (i < cn) {
    int2 p = bE[slot];
    float d = deg[p.x];
    float w = d > 0.f ? rsqrtf(d) * __int_as_float(p.y) : 0.f;
    bE[slot].y = __float_as_int(w);
  }
}

// FMA of one bf16-packed row (int4e = 8 bf16) into 8-col accumulator A
#define FMA8(A, Wt, R) { \
  A[0] = fmaf(Wt, __uint_as_float((unsigned)R.x << 16), A[0]); \
  A[1] = fmaf(Wt, __uint_as_float((unsigned)R.x & 0xffff0000u), A[1]); \
  A[2] = fmaf(Wt, __uint_as_float((unsigned)R.y << 16), A[2]); \
  A[3] = fmaf(Wt, __uint_as_float((unsigned)R.y & 0xffff0000u), A[3]); \
  A[4] = fmaf(Wt, __uint_as_float((unsigned)R.z << 16), A[4]); \
  A[5] = fmaf(Wt, __uint_as_float((unsigned)R.z & 0xffff0000u), A[5]); \
  A[6] = fmaf(Wt, __uint_as_float((unsigned)R.w << 16), A[6]); \
  A[7] = fmaf(Wt, __uint_as_float((unsigned)R.w & 0xffff0000u), A[7]); }

// ---- bf16-source gather: 16 lanes/node (16B each), 16 nodes/block, 8-deep ILP ----
template <int PHASE>
__global__ __launch_bounds__(256) void k_gather(
    const int* __restrict__ cnt, const int2* __restrict__ bE,
    const float* __restrict__ deg, const float* __restrict__ H,
    ushort_t* __restrict__ U) {
  int g = threadIdx.x >> 4, lane = threadIdx.x & 15;
  int node = blockIdx.x * 16 + g;
  if (node >= N_NODES) return;
  int cn = cnt[node]; if (cn > CAP) cn = CAP;
  const int2* be = bE + node * CAP;
  const ushort_t* sb = U + (PHASE == 1 ? 128 : 256) + lane * 8;
  float dc = deg[node];
  float sc = dc > 0.f ? -rsqrtf(dc) : 0.f;   // -dinv[c], factored out of the sum

  float a0[8] = {}, a1[8] = {}, a2[8] = {}, a3[8] = {};
  float a4[8] = {}, a5[8] = {}, a6[8] = {}, a7[8] = {};
  int i = 0;
  for (; i + 8 <= cn; i += 8) {
    int4e p0 = __builtin_nontemporal_load((const int4e*)(be + i));
    int4e p1 = __builtin_nontemporal_load((const int4e*)(be + i + 2));
    int4e p2 = __builtin_nontemporal_load((const int4e*)(be + i + 4));
    int4e p3 = __builtin_nontemporal_load((const int4e*)(be + i + 6));
    int4e r0 = *(const int4e*)(sb + (size_t)p0.x * 512);
    int4e r1 = *(const int4e*)(sb + (size_t)p0.z * 512);
    int4e r2 = *(const int4e*)(sb + (size_t)p1.x * 512);
    int4e r3 = *(const int4e*)(sb + (size_t)p1.z * 512);
    int4e r4 = *(const int4e*)(sb + (size_t)p2.x * 512);
    int4e r5 = *(const int4e*)(sb + (size_t)p2.z * 512);
    int4e r6 = *(const int4e*)(sb + (size_t)p3.x * 512);
    int4e r7 = *(const int4e*)(sb + (size_t)p3.z * 512);
    FMA8(a0, __int_as_float(p0.y), r0); FMA8(a1, __int_as_float(p0.w), r1);
    FMA8(a2, __int_as_float(p1.y), r2); FMA8(a3, __int_as_float(p1.w), r3);
    FMA8(a4, __int_as_float(p2.y), r4); FMA8(a5, __int_as_float(p2.w), r5);
    FMA8(a6, __int_as_float(p3.y), r6); FMA8(a7, __int_as_float(p3.w), r7);
  }
  for (; i + 4 <= cn; i += 4) {
    int4e p0 = __builtin_nontemporal_load((const int4e*)(be + i));
    int4e p1 = __builtin_nontemporal_load((const int4e*)(be + i + 2));
    int4e r0 = *(const int4e*)(sb + (size_t)p0.x * 512);
    int4e r1 = *(const int4e*)(sb + (size_t)p0.z * 512);
    int4e r2 = *(const int4e*)(sb + (size_t)p1.x * 512);
    int4e r3 = *(const int4e*)(sb + (size_t)p1.z * 512);
    FMA8(a0, __int_as_float(p0.y), r0); FMA8(a1, __int_as_float(p0.w), r1);
    FMA8(a2, __int_as_float(p1.y), r2); FMA8(a3, __int_as_float(p1.w), r3);
  }
  for (; i < cn; ++i) {
    int2 p = be[i];
    int4e r0 = *(const int4e*)(sb + (size_t)p.x * 512);
    FMA8(a0, __int_as_float(p.y), r0);
  }
  float o[8];
#pragma unroll
  for (int j = 0; j < 8; ++j)
    o[j] = sc * (((a0[j] + a1[j]) + (a2[j] + a3[j])) +
                 ((a4[j] + a5[j]) + (a6[j] + a7[j])));

  if (PHASE == 1) {
    ushort8e u;
#pragma unroll
    for (int j = 0; j < 8; ++j) u[j] = f2bf(o[j]);
    __builtin_nontemporal_store(u, (ushort8e*)(U + (size_t)node * 512 + 256 + lane * 8));
  } else {
    float4 hlo = *(const float4*)(H + (size_t)node * 128 + lane * 8);
    float4 hhi = *(const float4*)(H + (size_t)node * 128 + lane * 8 + 4);
    ushort8e u;
    u[0] = f2bf(2.f * o[0] - hlo.x); u[1] = f2bf(2.f * o[1] - hlo.y);
    u[2] = f2bf(2.f * o[2] - hlo.z); u[3] = f2bf(2.f * o[3] - hlo.w);
    u[4] = f2bf(2.f * o[4] - hhi.x); u[5] = f2bf(2.f * o[5] - hhi.y);
    u[6] = f2bf(2.f * o[6] - hhi.z); u[7] = f2bf(2.f * o[7] - hhi.w);
    __builtin_nontemporal_store(u, (ushort8e*)(U + (size_t)node * 512 + 384 + lane * 8));
  }
}

// ---- fused GEMM: same 2-phase counted-vmcnt pipeline, 512 threads (8 waves of
// 32x64) on the 128x128 tile -> 16 waves/CU (2x TLP) at same 64KB LDS ----
__global__ __launch_bounds__(512, 4) void k_gemm(
    const ushort_t* __restrict__ U, const ushort_t* __restrict__ Bt,
    const float* __restrict__ bias, const float* __restrict__ C,
    float* __restrict__ out) {
  __shared__ char ldsRaw[65536];     // 2 x (16K A + 16K B); epilogue reuses as f32 tile
  char* ldsA0 = ldsRaw;
  char* ldsB0 = ldsRaw + 16384;
  char* ldsA1 = ldsRaw + 32768;
  char* ldsB1 = ldsRaw + 49152;
  float* ldsF = (float*)ldsRaw;

  const int tid = threadIdx.x;
  const int lane = tid & 63;
  const int w = tid >> 6;            // 8 waves
  const int wr = w >> 1, wc = w & 1; // 4x2 wave grid: 32-row x 64-col sub-tiles
  // XCD-bijective swizzle: 3128 = 8*391; 4 n-tiles of an m-panel stay in one XCD
  const int b = blockIdx.x;
  const int g = (b & 7) * 391 + (b >> 3);
  const int m0 = (g >> 2) * 128;
  const int n0 = (g & 3) * 128;
  const int l15 = lane & 15;
  const int l4 = lane >> 4;

  // stage half h of tile kt: each thread 1 A + 1 B global_load_lds (16B)
  auto stage_half = [&](int kt, char* la_base, char* lb_base, int h) {
    const int k0 = kt * 64;
    int s = h * 512 + tid;
    int row = s >> 3;
    int cs = (s & 7) ^ (row & 7);          // inverse-swizzled global source chunk
    const ushort_t* ga = U + (size_t)(m0 + row) * 512 + k0 + cs * 8;
    const ushort_t* gb = Bt + (size_t)(n0 + row) * 512 + k0 + cs * 8;
    char* la = la_base + (h * 512 + (tid & 448)) * 16;    // wave-uniform base
    char* lb = lb_base + (h * 512 + (tid & 448)) * 16;
    __builtin_amdgcn_global_load_lds((const __attribute__((address_space(1))) void*)ga,
                                     (__attribute__((address_space(3))) void*)la, 16, 0, 0);
    __builtin_amdgcn_global_load_lds((const __attribute__((address_space(1))) void*)gb,
                                     (__attribute__((address_space(3))) void*)lb, 16, 0, 0);
  };

  // C prefetch (epilogue operand), nontemporal (single-touch, keep out of L2)
  const int fcol = tid & 31;
  const int rbase = tid >> 5;              // 0..15
  float cpre[8];
#pragma unroll
  for (int half = 0; half < 2; ++half)
#pragma unroll
    for (int k = 0; k < 4; ++k) {
      int n = m0 + half * 64 + rbase + k * 16;
      int dg = (n0 >> 2) + fcol;
      cpre[half * 4 + k] = (n < N_NODES)
          ? __builtin_nontemporal_load(C + (size_t)n * 128 + dg) : 0.f;
    }

  // loop-invariant swizzled LDS read offsets (sub-tile rows are multiples of 16)
  int offA[2][2], offB[2][4];
#pragma unroll
  for (int ks = 0; ks < 2; ++ks) {
    int slot = ((ks * 4 + l4) ^ (l15 & 7)) * 16;
#pragma unroll
    for (int i = 0; i < 2; ++i)
      offA[ks][i] = (wr * 32 + i * 16 + l15) * 128 + slot;
#pragma unroll
    for (int i = 0; i < 4; ++i)
      offB[ks][i] = (wc * 64 + i * 16 + l15) * 128 + slot;
  }

  f32x4 acc[2][4] = {};

  stage_half(0, ldsA0, ldsB0, 0);
  stage_half(0, ldsA0, ldsB0, 1);          // 4 loads/thread outstanding

  for (int kt = 0; kt < 8; ++kt) {
    char* curA = (kt & 1) ? ldsA1 : ldsA0;
    char* curB = (kt & 1) ? ldsB1 : ldsB0;
    char* nA = (kt & 1) ? ldsA0 : ldsA1;
    char* nB = (kt & 1) ? ldsB0 : ldsB1;
    if (kt < 7) {
      stage_half(kt + 1, nA, nB, 0);       // 2 loads -> 6 outstanding
      asm volatile("s_waitcnt vmcnt(2)" ::: "memory");  // stage(kt) landed; half0(kt+1) in flight
    } else {
      asm volatile("s_waitcnt vmcnt(0)" ::: "memory");
    }
    __builtin_amdgcn_s_barrier();          // A: cur fully staged for all threads
    __builtin_amdgcn_sched_barrier(0);

    // ---- sub-phase ks=0 ----
    {
      bf16x8 af[2], bfr[4];
#pragma unroll
      for (int mi = 0; mi < 2; ++mi) af[mi] = *(const bf16x8*)(curA + offA[0][mi]);
#pragma unroll
      for (int ni = 0; ni < 4; ++ni) bfr[ni] = *(const bf16x8*)(curB + offB[0][ni]);
      asm volatile("s_waitcnt lgkmcnt(0)" ::: "memory");
      __builtin_amdgcn_sched_barrier(0);
      __builtin_amdgcn_s_setprio(1);
#pragma unroll
      for (int mi = 0; mi < 2; ++mi)
#pragma unroll
        for (int ni = 0; ni < 4; ++ni)
          acc[mi][ni] = __builtin_amdgcn_mfma_f32_16x16x32_bf16(af[mi], bfr[ni], acc[mi][ni], 0, 0, 0);
      __builtin_amdgcn_s_setprio(0);
    }
    if (kt < 7) stage_half(kt + 1, nA, nB, 1);  // 2 loads
    // ---- sub-phase ks=1 ----
    {
      bf16x8 af[2], bfr[4];
#pragma unroll
      for (int mi = 0; mi < 2; ++mi) af[mi] = *(const bf16x8*)(curA + offA[1][mi]);
#pragma unroll
      for (int ni = 0; ni < 4; ++ni) bfr[ni] = *(const bf16x8*)(curB + offB[1][ni]);
      asm volatile("s_waitcnt lgkmcnt(0)" ::: "memory");
      __builtin_amdgcn_sched_barrier(0);
      __builtin_amdgcn_s_setprio(1);
#pragma unroll
      for (int mi = 0; mi < 2; ++mi)
#pragma unroll
        for (int ni = 0; ni < 4; ++ni)
          acc[mi][ni] = __builtin_amdgcn_mfma_f32_16x16x32_bf16(af[mi], bfr[ni], acc[mi][ni], 0, 0, 0);
      __builtin_amdgcn_s_setprio(0);
    }
    __builtin_amdgcn_s_barrier();          // B: all done reading cur; safe to overwrite
  }

  // epilogue: two row-halves through LDS, then fused LSTM elementwise
#pragma unroll
  for (int half = 0; half < 2; ++half) {
    if ((wr >> 1) == half) {               // waves wr {0,1} -> rows 0..63; {2,3} -> 64..127
#pragma unroll
      for (int ni = 0; ni < 4; ++ni) {
        int col = wc * 64 + ni * 16 + l15;
        float bv = bias[n0 + col];
#pragma unroll
        for (int mi = 0; mi < 2; ++mi)
#pragma unroll
          for (int r = 0; r < 4; ++r)
            ldsF[((wr & 1) * 32 + mi * 16 + l4 * 4 + r) * 132 + col] = acc[mi][ni][r] + bv;
      }
    }
    __syncthreads();
#pragma unroll
    for (int k = 0; k < 4; ++k) {
      int p = tid + k * 512;
      int rl = p >> 5, f = p & 31;
      int n = m0 + half * 64 + rl;
      if (n < N_NODES) {
        float4 pre = *(const float4*)&ldsF[rl * 132 + f * 4];
        int dg = (n0 >> 2) + f;
        float ig = __builtin_amdgcn_rcpf(1.f + __expf(-pre.x));
        float fg = __builtin_amdgcn_rcpf(1.f + __expf(-pre.y));
        float ec = __expf(-2.f * fabsf(pre.z));
        float tg = __builtin_copysignf((1.f - ec) * __builtin_amdgcn_rcpf(1.f + ec), pre.z);
        float og = __builtin_amdgcn_rcpf(1.f + __expf(-pre.w));
        float cOld = cpre[half * 4 + k];
        float cn = fg * cOld + ig * tg;
        float en = __expf(-2.f * fabsf(cn));
        float th = __builtin_copysignf((1.f - en) * __builtin_amdgcn_rcpf(1.f + en), cn);
        __builtin_nontemporal_store(og * th, out + (size_t)n * 128 + dg);
      }
    }
    __syncthreads();
  }
}

extern "C" void kernel_launch(void* const* d_in, const int* in_sizes, int n_in,
                              void* d_out, int out_size, void* d_ws, size_t ws_size,
                              hipStream_t stream) {
  const float* X  = (const float*)d_in[0];
  const int*   ei = (const int*)d_in[1];
  const float* ew = (const float*)d_in[2];
  const float* H  = (const float*)d_in[3];
  const float* C  = (const float*)d_in[4];
  const float* W  = (const float*)d_in[5];
  const float* b  = (const float*)d_in[6];
  const float* cW = (const float*)d_in[7];
  const float* cb = (const float*)d_in[8];
  float* out = (float*)d_out;
  char* ws = (char*)d_ws;

  float*    deg  = (float*)(ws);                 // 0.5 MB
  int*      cnt  = (int*)(ws + 0x80000);         // 0.5 MB
  int2*     bE   = (int2*)(ws + 0x100000);       // 51.2 MB CAP buckets (row, w)
  ushort_t* U    = (ushort_t*)(ws + 0x3500000);  // 100096 x 512 bf16 = 102.5 MB
  ushort_t* Bt   = (ushort_t*)(ws + 0x9700000);  // 512 KB
  float*    bias = (float*)(ws + 0x9780000);     // 2 KB

  hipMemsetAsync(ws, 0, 0x100000, stream);       // zero deg + cnt

  k_misc<<<27128, 256, 0, stream>>>(ei, ew, X, H, deg, cnt, bE, U, W, b, cW, cb, Bt, bias);
  k_scale<<<N_NODES * CAP / 256, 256, 0, stream>>>(cnt, deg, bE);
  k_gather<1><<<(N_NODES + 15) / 16, 256, 0, stream>>>(cnt, bE, deg, H, U);
  k_gather<2><<<(N_NODES + 15) / 16, 256, 0, stream>>>(cnt, bE, deg, H, U);
  k_gemm<<<3128, 512, 0, stream>>>(U, Bt, bias, C, out);
}